// Round 1
// baseline (1961.085 us; speedup 1.0000x reference)
//
#include <hip/hip_runtime.h>
#include <math.h>

#define DIM 768
#define HEADS 12
#define HD 64
#define HIDDEN 3072
#define BATCH 2
#define SEQ 2048
#define ROWS (BATCH*SEQ)   // 4096
#define SCALE 0.125f
#define LN_EPS 1e-5f

// ---------------- LayerNorm: one block (256 thr) per row of 768 ----------------
__launch_bounds__(256)
__global__ void ln_kernel(const float* __restrict__ x, const float* __restrict__ g,
                          const float* __restrict__ b, float* __restrict__ out) {
    int row = blockIdx.x;
    const float* xr = x + (size_t)row * DIM;
    int t = threadIdx.x;
    float v0 = xr[t], v1 = xr[t + 256], v2 = xr[t + 512];
    float s  = v0 + v1 + v2;
    float ss = v0 * v0 + v1 * v1 + v2 * v2;
    #pragma unroll
    for (int o = 32; o >= 1; o >>= 1) {
        s  += __shfl_xor(s, o);
        ss += __shfl_xor(ss, o);
    }
    __shared__ float rs[4], rss[4];
    int wid = t >> 6, lane = t & 63;
    if (lane == 0) { rs[wid] = s; rss[wid] = ss; }
    __syncthreads();
    if (t == 0) {
        float S = 0.f, SS = 0.f;
        for (int i = 0; i < 4; i++) { S += rs[i]; SS += rss[i]; }
        rs[0] = S; rss[0] = SS;
    }
    __syncthreads();
    float mean = rs[0] * (1.0f / DIM);
    float var  = rss[0] * (1.0f / DIM) - mean * mean;
    float rstd = rsqrtf(var + LN_EPS);
    float* orow = out + (size_t)row * DIM;
    orow[t]       = (v0 - mean) * rstd * g[t]       + b[t];
    orow[t + 256] = (v1 - mean) * rstd * g[t + 256] + b[t + 256];
    orow[t + 512] = (v2 - mean) * rstd * g[t + 512] + b[t + 512];
}

// ---------------- Generic fp32 GEMM: C = A[M,K] @ W[K,N] + bias (+epilogue) ----
// EPI: 0 = bias, 1 = bias + exact GELU, 2 = bias + residual add
template<int EPI>
__launch_bounds__(256)
__global__ void gemm_kernel(const float* __restrict__ A, const float* __restrict__ W,
                            const float* __restrict__ bias, const float* __restrict__ res,
                            float* __restrict__ C, int M, int N, int K) {
    __shared__ float sA[16][68];  // [k][m], padded for alignment + banks
    __shared__ float sB[16][68];  // [k][n]
    int t  = threadIdx.x;
    int tx = t & 15, ty = t >> 4;
    int row0 = blockIdx.y * 64, col0 = blockIdx.x * 64;
    float acc[4][4] = {};

    for (int k0 = 0; k0 < K; k0 += 16) {
        {   // A tile 64x16, 4 consecutive k per thread
            int e = t * 4;
            int r = e >> 4, c = e & 15;
            float4 av = *(const float4*)(A + (size_t)(row0 + r) * K + k0 + c);
            sA[c + 0][r] = av.x; sA[c + 1][r] = av.y;
            sA[c + 2][r] = av.z; sA[c + 3][r] = av.w;
        }
        {   // W tile 16x64, coalesced
            int e = t * 4;
            int r = e >> 6, c = e & 63;
            float4 wv = *(const float4*)(W + (size_t)(k0 + r) * N + col0 + c);
            *(float4*)&sB[r][c] = wv;
        }
        __syncthreads();
        #pragma unroll
        for (int k = 0; k < 16; k++) {
            float4 av = *(const float4*)&sA[k][ty * 4];
            float4 bv = *(const float4*)&sB[k][tx * 4];
            float a_[4] = {av.x, av.y, av.z, av.w};
            float b_[4] = {bv.x, bv.y, bv.z, bv.w};
            #pragma unroll
            for (int i = 0; i < 4; i++)
                #pragma unroll
                for (int j = 0; j < 4; j++)
                    acc[i][j] = fmaf(a_[i], b_[j], acc[i][j]);
        }
        __syncthreads();
    }

    #pragma unroll
    for (int i = 0; i < 4; i++) {
        int gr = row0 + ty * 4 + i;
        float* cp = C + (size_t)gr * N + col0 + tx * 4;
        #pragma unroll
        for (int j = 0; j < 4; j++) {
            float v = acc[i][j] + bias[col0 + tx * 4 + j];
            if (EPI == 1) v = 0.5f * v * (1.f + erff(v * 0.70710678118654752f));
            if (EPI == 2) v += res[(size_t)gr * N + col0 + tx * 4 + j];
            cp[j] = v;
        }
    }
}

// ---------------- Fused attention with elevation mask (flash-style) ------------
// Per block: one (b, h, 64-query tile). Online softmax tracking sum(e) and
// sum(e*mask): out = sum(e*m*v) / (sum(e*m) + 1e-8*sum(e))  == reference.
__launch_bounds__(256)
__global__ void attn_kernel(const float* __restrict__ qkv, const float* __restrict__ elev,
                            const float* __restrict__ barrier_p, float* __restrict__ out) {
    int qb = blockIdx.x, h = blockIdx.y, b = blockIdx.z;
    int t = threadIdx.x;
    int r = t >> 2, c = t & 3;      // query row in tile, quad id
    __shared__ float Qs[64][68];
    __shared__ float Ks[64][68];
    __shared__ float Vs[64][68];
    __shared__ float Ps[64][68];
    __shared__ float Ei[64], Ej[64];
    float barrier = barrier_p[0];
    const float* base = qkv + (size_t)b * SEQ * 2304;
    int q0 = qb * 64;

    for (int e = t * 4; e < 4096; e += 1024) {
        int rr = e >> 6, dd = e & 63;
        *(float4*)&Qs[rr][dd] = *(const float4*)(base + (size_t)(q0 + rr) * 2304 + h * 64 + dd);
    }
    if (t < 64) Ei[t] = elev[(size_t)b * SEQ + q0 + t];

    float o[16];
    #pragma unroll
    for (int i = 0; i < 16; i++) o[i] = 0.f;
    float m = -1e30f, se = 0.f, sem = 0.f;

    for (int kt = 0; kt < SEQ / 64; kt++) {
        int k0 = kt * 64;
        __syncthreads();
        for (int e = t * 4; e < 4096; e += 1024) {
            int rr = e >> 6, dd = e & 63;
            *(float4*)&Ks[rr][dd] = *(const float4*)(base + (size_t)(k0 + rr) * 2304 + 768  + h * 64 + dd);
            *(float4*)&Vs[rr][dd] = *(const float4*)(base + (size_t)(k0 + rr) * 2304 + 1536 + h * 64 + dd);
        }
        if (t < 64) Ej[t] = elev[(size_t)b * SEQ + k0 + t];
        __syncthreads();

        // scores: 16 keys per thread (j = c*16 .. c*16+15)
        float s[16];
        #pragma unroll
        for (int jj = 0; jj < 16; jj++) s[jj] = 0.f;
        #pragma unroll
        for (int d4 = 0; d4 < 16; d4++) {
            float4 qv = *(const float4*)&Qs[r][d4 * 4];
            #pragma unroll
            for (int jj = 0; jj < 16; jj++) {
                float4 kv = *(const float4*)&Ks[c * 16 + jj][d4 * 4];
                s[jj] += qv.x * kv.x + qv.y * kv.y + qv.z * kv.z + qv.w * kv.w;
            }
        }
        #pragma unroll
        for (int jj = 0; jj < 16; jj++) s[jj] *= SCALE;

        float mx = s[0];
        #pragma unroll
        for (int jj = 1; jj < 16; jj++) mx = fmaxf(mx, s[jj]);
        mx = fmaxf(mx, __shfl_xor(mx, 1));
        mx = fmaxf(mx, __shfl_xor(mx, 2));
        float mnew = fmaxf(m, mx);

        float ei = Ei[r];
        float seadd = 0.f, semadd = 0.f;
        #pragma unroll
        for (int jj = 0; jj < 16; jj++) {
            int j = c * 16 + jj;
            float e = __expf(s[jj] - mnew);
            float z = barrier * (ei - Ej[j]);
            float sg = 1.f / (1.f + __expf(-z));
            float mk = fminf(fmaxf(sg, 1e-6f), 1.f);
            seadd  += e;
            semadd += e * mk;
            Ps[r][j] = e * mk;
        }
        seadd  += __shfl_xor(seadd, 1);  seadd  += __shfl_xor(seadd, 2);
        semadd += __shfl_xor(semadd, 1); semadd += __shfl_xor(semadd, 2);

        float alpha = __expf(m - mnew);
        m = mnew;
        se  = se  * alpha + seadd;
        sem = sem * alpha + semadd;
        #pragma unroll
        for (int i = 0; i < 16; i++) o[i] *= alpha;
        __syncthreads();

        // PV: dims d = c*16 .. c*16+15
        for (int j = 0; j < 64; j++) {
            float pv = Ps[r][j];
            #pragma unroll
            for (int i4 = 0; i4 < 4; i4++) {
                float4 vv = *(const float4*)&Vs[j][c * 16 + i4 * 4];
                o[i4 * 4 + 0] += pv * vv.x;
                o[i4 * 4 + 1] += pv * vv.y;
                o[i4 * 4 + 2] += pv * vv.z;
                o[i4 * 4 + 3] += pv * vv.w;
            }
        }
    }

    float inv = 1.f / (sem + 1e-8f * se);
    float* op = out + ((size_t)(b * SEQ + q0 + r)) * DIM + h * 64 + c * 16;
    #pragma unroll
    for (int i4 = 0; i4 < 4; i4++) {
        float4 v;
        v.x = o[i4 * 4 + 0] * inv; v.y = o[i4 * 4 + 1] * inv;
        v.z = o[i4 * 4 + 2] * inv; v.w = o[i4 * 4 + 3] * inv;
        *(float4*)(op + i4 * 4) = v;
    }
}

extern "C" void kernel_launch(void* const* d_in, const int* in_sizes, int n_in,
                              void* d_out, int out_size, void* d_ws, size_t ws_size,
                              hipStream_t stream) {
    const float* x      = (const float*)d_in[0];
    const float* elev   = (const float*)d_in[1];
    const float* qkv_w  = (const float*)d_in[2];
    const float* qkv_b  = (const float*)d_in[3];
    const float* proj_w = (const float*)d_in[4];
    const float* proj_b = (const float*)d_in[5];
    const float* ln1_g  = (const float*)d_in[6];
    const float* ln1_b  = (const float*)d_in[7];
    const float* ln2_g  = (const float*)d_in[8];
    const float* ln2_b  = (const float*)d_in[9];
    const float* fc1_w  = (const float*)d_in[10];
    const float* fc1_b  = (const float*)d_in[11];
    const float* fc2_w  = (const float*)d_in[12];
    const float* fc2_b  = (const float*)d_in[13];
    const float* barrier= (const float*)d_in[14];
    float* out = (float*)d_out;
    float* ws  = (float*)d_ws;

    // workspace layout (floats):
    // [0, 12582912): h (first 3145728) + qkv (next 9437184); later overlaid by f1 (12582912)
    // [12582912, 15728640): attn_out; later overlaid by h2
    float* h    = ws;
    float* qkv  = ws + 3145728;
    float* f1   = ws;
    float* attn = ws + 12582912;
    float* h2   = ws + 12582912;

    ln_kernel<<<ROWS, 256, 0, stream>>>(x, ln1_g, ln1_b, h);
    gemm_kernel<0><<<dim3(2304 / 64, 4096 / 64), 256, 0, stream>>>(
        h, qkv_w, qkv_b, nullptr, qkv, 4096, 2304, 768);
    attn_kernel<<<dim3(SEQ / 64, HEADS, BATCH), 256, 0, stream>>>(qkv, elev, barrier, attn);
    gemm_kernel<2><<<dim3(768 / 64, 4096 / 64), 256, 0, stream>>>(
        attn, proj_w, proj_b, x, out, 4096, 768, 768);
    ln_kernel<<<ROWS, 256, 0, stream>>>(out, ln2_g, ln2_b, h2);
    gemm_kernel<1><<<dim3(3072 / 64, 4096 / 64), 256, 0, stream>>>(
        h2, fc1_w, fc1_b, nullptr, f1, 4096, 3072, 768);
    gemm_kernel<2><<<dim3(768 / 64, 4096 / 64), 256, 0, stream>>>(
        f1, fc2_w, fc2_b, out, out, 4096, 768, 3072);
}

// Round 2
// 466.815 us; speedup vs baseline: 4.2010x; 4.2010x over previous
//
#include <hip/hip_runtime.h>
#include <math.h>

#define DIM 768
#define HEADS 12
#define SEQ 2048
#define ROWS 4096
#define LN_EPS 1e-5f

typedef __attribute__((ext_vector_type(8))) short short8;
typedef __attribute__((ext_vector_type(4))) float floatx4;
typedef unsigned short ushort_t;

__device__ __forceinline__ ushort_t f2bf(float x) {
    unsigned u = __float_as_uint(x);
    u += 0x7fff + ((u >> 16) & 1);
    return (ushort_t)(u >> 16);
}

__device__ __forceinline__ void gload_lds16(const void* g, void* l) {
    __builtin_amdgcn_global_load_lds((const __attribute__((address_space(1))) void*)g,
                                     (__attribute__((address_space(3))) void*)l, 16, 0, 0);
}

// ---------- weight convert + transpose: W[K][N] fp32 -> WT[N][K] bf16 ----------
__launch_bounds__(256)
__global__ void wconv_kernel(const float* __restrict__ W, ushort_t* __restrict__ WT,
                             int K, int N) {
    __shared__ __align__(16) ushort_t s[64][72];
    int k0 = blockIdx.y * 64, n0 = blockIdx.x * 64;
    int t = threadIdx.x;
    int rr0 = t >> 4, c4 = (t & 15) * 4;
    for (int rr = rr0; rr < 64; rr += 16) {
        float4 w = *(const float4*)(W + (size_t)(k0 + rr) * N + n0 + c4);
        s[c4 + 0][rr] = f2bf(w.x); s[c4 + 1][rr] = f2bf(w.y);
        s[c4 + 2][rr] = f2bf(w.z); s[c4 + 3][rr] = f2bf(w.w);
    }
    __syncthreads();
    int nl = t >> 2, kq = (t & 3) * 16;
    uint4 a = *(const uint4*)&s[nl][kq];
    uint4 b = *(const uint4*)&s[nl][kq + 8];
    *(uint4*)(WT + (size_t)(n0 + nl) * K + k0 + kq) = a;
    *(uint4*)(WT + (size_t)(n0 + nl) * K + k0 + kq + 8) = b;
}

// ---------- LayerNorm fp32 in -> bf16 out ----------
__launch_bounds__(256)
__global__ void ln_kernel(const float* __restrict__ x, const float* __restrict__ g,
                          const float* __restrict__ b, ushort_t* __restrict__ out) {
    int row = blockIdx.x;
    const float* xr = x + (size_t)row * DIM;
    int t = threadIdx.x;
    float v0 = xr[t], v1 = xr[t + 256], v2 = xr[t + 512];
    float s  = v0 + v1 + v2;
    float ss = v0 * v0 + v1 * v1 + v2 * v2;
    #pragma unroll
    for (int o = 32; o >= 1; o >>= 1) { s += __shfl_xor(s, o); ss += __shfl_xor(ss, o); }
    __shared__ float rs[4], rss[4];
    int wid = t >> 6, lane = t & 63;
    if (lane == 0) { rs[wid] = s; rss[wid] = ss; }
    __syncthreads();
    if (t == 0) {
        float S = 0.f, SS = 0.f;
        for (int i = 0; i < 4; i++) { S += rs[i]; SS += rss[i]; }
        rs[0] = S; rss[0] = SS;
    }
    __syncthreads();
    float mean = rs[0] * (1.0f / DIM);
    float var  = rss[0] * (1.0f / DIM) - mean * mean;
    float rstd = rsqrtf(var + LN_EPS);
    ushort_t* orow = out + (size_t)row * DIM;
    orow[t]       = f2bf((v0 - mean) * rstd * g[t]       + b[t]);
    orow[t + 256] = f2bf((v1 - mean) * rstd * g[t + 256] + b[t + 256]);
    orow[t + 512] = f2bf((v2 - mean) * rstd * g[t + 512] + b[t + 512]);
}

// ---------- bf16 MFMA GEMM: C = A[M,K] @ WT[N,K]^T + bias ----------
// EPI 0: qkv special (write q/k row-major bf16, v transposed bf16 per head)
// EPI 1: gelu -> bf16 row-major   EPI 2: + res(fp32) -> fp32
template<int EPI>
__launch_bounds__(256)
__global__ void gemm_bf16(const ushort_t* __restrict__ A, const ushort_t* __restrict__ WT,
                          const float* __restrict__ bias, const float* __restrict__ res,
                          float* __restrict__ outF, ushort_t* __restrict__ outB,
                          ushort_t* __restrict__ qb, ushort_t* __restrict__ kb,
                          ushort_t* __restrict__ vb, int N, int K) {
    __shared__ __align__(16) ushort_t sA[128 * 32];
    __shared__ __align__(16) ushort_t sB[128 * 32];
    int t = threadIdx.x;
    int row0 = blockIdx.y * 128, col0 = blockIdx.x * 128;
    int wid = t >> 6, lane = t & 63;
    int wm = wid >> 1, wn = wid & 1;
    int cl = lane & 15, quad = lane >> 4;

    floatx4 acc[4][4];
    #pragma unroll
    for (int i = 0; i < 4; i++)
        #pragma unroll
        for (int j = 0; j < 4; j++) { floatx4 z = {0.f, 0.f, 0.f, 0.f}; acc[i][j] = z; }

    for (int k0 = 0; k0 < K; k0 += 32) {
        #pragma unroll
        for (int i = 0; i < 2; i++) {
            int c = i * 256 + t;
            int r = c >> 2, sub = c & 3;
            gload_lds16(A  + (size_t)(row0 + r) * K + k0 + sub * 8, &sA[c * 8]);
            gload_lds16(WT + (size_t)(col0 + r) * K + k0 + sub * 8, &sB[c * 8]);
        }
        __syncthreads();
        short8 a[4], b[4];
        #pragma unroll
        for (int i = 0; i < 4; i++)
            a[i] = *(const short8*)&sA[(wm * 64 + i * 16 + cl) * 32 + quad * 8];
        #pragma unroll
        for (int j = 0; j < 4; j++)
            b[j] = *(const short8*)&sB[(wn * 64 + j * 16 + cl) * 32 + quad * 8];
        #pragma unroll
        for (int i = 0; i < 4; i++)
            #pragma unroll
            for (int j = 0; j < 4; j++)
                acc[i][j] = __builtin_amdgcn_mfma_f32_16x16x32_bf16(a[i], b[j], acc[i][j], 0, 0, 0);
        __syncthreads();
    }

    #pragma unroll
    for (int i = 0; i < 4; i++) {
        #pragma unroll
        for (int j = 0; j < 4; j++) {
            int gcol = col0 + wn * 64 + j * 16 + cl;
            float bv = bias[gcol];
            #pragma unroll
            for (int rg = 0; rg < 4; rg++) {
                int grow = row0 + wm * 64 + i * 16 + quad * 4 + rg;
                float v = acc[i][j][rg] + bv;
                if (EPI == 0) {
                    int which = gcol / 768;
                    int hc = gcol - which * 768;
                    int h = hc >> 6, d = hc & 63;
                    int b_ = grow >> 11, n = grow & 2047;
                    size_t bh = (size_t)(b_ * 12 + h);
                    ushort_t bf = f2bf(v);
                    if (which == 0)      qb[(bh * 2048 + n) * 64 + d] = bf;
                    else if (which == 1) kb[(bh * 2048 + n) * 64 + d] = bf;
                    else                 vb[(bh * 64 + d) * 2048 + n] = bf;
                } else if (EPI == 1) {
                    v = 0.5f * v * (1.f + erff(v * 0.70710678118654752f));
                    outB[(size_t)grow * N + gcol] = f2bf(v);
                } else {
                    v += res[(size_t)grow * N + gcol];
                    outF[(size_t)grow * N + gcol] = v;
                }
            }
        }
    }
}

// ---------- MFMA flash attention with elevation mask ----------
__launch_bounds__(256)
__global__ void attn_mfma(const ushort_t* __restrict__ qb, const ushort_t* __restrict__ kb,
                          const ushort_t* __restrict__ vb, const float* __restrict__ elev,
                          const float* __restrict__ barrier_p, ushort_t* __restrict__ attn) {
    __shared__ __align__(16) ushort_t Qs[64 * 64];
    __shared__ __align__(16) ushort_t Ks[64 * 64];
    __shared__ __align__(16) ushort_t Vt[64 * 64];
    __shared__ __align__(16) ushort_t Ps[64 * 64];
    __shared__ float Ei[64], Ej[64];
    int qt = blockIdx.x, h = blockIdx.y, b = blockIdx.z;
    int t = threadIdx.x, wid = t >> 6, lane = t & 63;
    int cl = lane & 15, quad = lane >> 4;
    int q0 = qt * 64;
    size_t bh = (size_t)(b * 12 + h);
    float barrier = barrier_p[0];

    const ushort_t* qbase = qb + (bh * 2048 + q0) * 64;
    #pragma unroll
    for (int i = 0; i < 2; i++) {
        int c = i * 256 + t;
        gload_lds16(qbase + c * 8, &Qs[c * 8]);
    }
    if (t < 64) Ei[t] = elev[(size_t)b * 2048 + q0 + t];

    floatx4 o[4];
    #pragma unroll
    for (int j = 0; j < 4; j++) { floatx4 z = {0.f, 0.f, 0.f, 0.f}; o[j] = z; }
    float mrow[4], se[4], sem[4];
    #pragma unroll
    for (int r = 0; r < 4; r++) { mrow[r] = -1e30f; se[r] = 0.f; sem[r] = 0.f; }

    for (int kt = 0; kt < 32; kt++) {
        int k0 = kt * 64;
        const ushort_t* kbase = kb + (bh * 2048 + k0) * 64;
        const ushort_t* vbase = vb + bh * 64 * 2048 + k0;
        #pragma unroll
        for (int i = 0; i < 2; i++) {
            int c = i * 256 + t;
            gload_lds16(kbase + c * 8, &Ks[c * 8]);
            int r = c >> 3, sub = c & 7;
            gload_lds16(vbase + (size_t)r * 2048 + sub * 8, &Vt[c * 8]);
        }
        if (t < 64) Ej[t] = elev[(size_t)b * 2048 + k0 + t];
        __syncthreads();

        // S = Q K^T  (rows wid*16..+16, cols 0..63)
        floatx4 s[4];
        #pragma unroll
        for (int j = 0; j < 4; j++) { floatx4 z = {0.f, 0.f, 0.f, 0.f}; s[j] = z; }
        #pragma unroll
        for (int kh = 0; kh < 2; kh++) {
            short8 aq = *(const short8*)&Qs[(wid * 16 + cl) * 64 + kh * 32 + quad * 8];
            #pragma unroll
            for (int nt = 0; nt < 4; nt++) {
                short8 bk = *(const short8*)&Ks[(nt * 16 + cl) * 64 + kh * 32 + quad * 8];
                s[nt] = __builtin_amdgcn_mfma_f32_16x16x32_bf16(aq, bk, s[nt], 0, 0, 0);
            }
        }

        float ej[4];
        #pragma unroll
        for (int nt = 0; nt < 4; nt++) ej[nt] = Ej[nt * 16 + cl];

        #pragma unroll
        for (int rg = 0; rg < 4; rg++) {
            float eiv = Ei[wid * 16 + quad * 4 + rg];
            float sv[4];
            float mx = -1e30f;
            #pragma unroll
            for (int nt = 0; nt < 4; nt++) { sv[nt] = s[nt][rg] * 0.125f; mx = fmaxf(mx, sv[nt]); }
            mx = fmaxf(mx, __shfl_xor(mx, 1));
            mx = fmaxf(mx, __shfl_xor(mx, 2));
            mx = fmaxf(mx, __shfl_xor(mx, 4));
            mx = fmaxf(mx, __shfl_xor(mx, 8));
            float mnew = fmaxf(mrow[rg], mx);
            float alpha = __expf(mrow[rg] - mnew);
            float seadd = 0.f, semadd = 0.f;
            #pragma unroll
            for (int nt = 0; nt < 4; nt++) {
                float e = __expf(sv[nt] - mnew);
                float z = barrier * (eiv - ej[nt]);
                float sg = 1.f / (1.f + __expf(-z));
                sg = fminf(fmaxf(sg, 1e-6f), 1.f);
                float p = e * sg;
                seadd += e; semadd += p;
                Ps[(wid * 16 + quad * 4 + rg) * 64 + nt * 16 + cl] = f2bf(p);
            }
            seadd  += __shfl_xor(seadd, 1);  seadd  += __shfl_xor(seadd, 2);
            seadd  += __shfl_xor(seadd, 4);  seadd  += __shfl_xor(seadd, 8);
            semadd += __shfl_xor(semadd, 1); semadd += __shfl_xor(semadd, 2);
            semadd += __shfl_xor(semadd, 4); semadd += __shfl_xor(semadd, 8);
            mrow[rg] = mnew;
            se[rg]  = se[rg]  * alpha + seadd;
            sem[rg] = sem[rg] * alpha + semadd;
            #pragma unroll
            for (int dt = 0; dt < 4; dt++) o[dt][rg] *= alpha;
        }

        // O += P V   (P rows wid*16..+16 from LDS, V^T tiles)
        #pragma unroll
        for (int kh = 0; kh < 2; kh++) {
            short8 ap = *(const short8*)&Ps[(wid * 16 + cl) * 64 + kh * 32 + quad * 8];
            #pragma unroll
            for (int dt = 0; dt < 4; dt++) {
                short8 bv = *(const short8*)&Vt[(dt * 16 + cl) * 64 + kh * 32 + quad * 8];
                o[dt] = __builtin_amdgcn_mfma_f32_16x16x32_bf16(ap, bv, o[dt], 0, 0, 0);
            }
        }
        __syncthreads();
    }

    #pragma unroll
    for (int rg = 0; rg < 4; rg++) {
        float inv = 1.f / (sem[rg] + 1e-8f * se[rg]);
        int grow = b * 2048 + q0 + wid * 16 + quad * 4 + rg;
        #pragma unroll
        for (int dt = 0; dt < 4; dt++)
            attn[(size_t)grow * 768 + h * 64 + dt * 16 + cl] = f2bf(o[dt][rg] * inv);
    }
}

extern "C" void kernel_launch(void* const* d_in, const int* in_sizes, int n_in,
                              void* d_out, int out_size, void* d_ws, size_t ws_size,
                              hipStream_t stream) {
    const float* x      = (const float*)d_in[0];
    const float* elev   = (const float*)d_in[1];
    const float* qkv_w  = (const float*)d_in[2];
    const float* qkv_b  = (const float*)d_in[3];
    const float* proj_w = (const float*)d_in[4];
    const float* proj_b = (const float*)d_in[5];
    const float* ln1_g  = (const float*)d_in[6];
    const float* ln1_b  = (const float*)d_in[7];
    const float* ln2_g  = (const float*)d_in[8];
    const float* ln2_b  = (const float*)d_in[9];
    const float* fc1_w  = (const float*)d_in[10];
    const float* fc1_b  = (const float*)d_in[11];
    const float* fc2_w  = (const float*)d_in[12];
    const float* fc2_b  = (const float*)d_in[13];
    const float* barrier= (const float*)d_in[14];
    float* out = (float*)d_out;
    char* ws = (char*)d_ws;

    // byte offsets (region A overlaid by f1)
    ushort_t* h    = (ushort_t*)(ws + 0);         // 6291456 B
    ushort_t* qb   = (ushort_t*)(ws + 6291456);   // 6291456
    ushort_t* kb   = (ushort_t*)(ws + 12582912);  // 6291456
    ushort_t* vb   = (ushort_t*)(ws + 18874368);  // 6291456
    ushort_t* f1   = (ushort_t*)(ws + 0);         // 25165824 (overlays h,qb,kb,vb)
    ushort_t* attn = (ushort_t*)(ws + 25165824);  // 6291456
    ushort_t* h2   = (ushort_t*)(ws + 31457280);  // 6291456
    ushort_t* qkvT = (ushort_t*)(ws + 37748736);  // 3538944
    ushort_t* projT= (ushort_t*)(ws + 41287680);  // 1179648
    ushort_t* fc1T = (ushort_t*)(ws + 42467328);  // 4718592
    ushort_t* fc2T = (ushort_t*)(ws + 47185920);  // 4718592

    wconv_kernel<<<dim3(2304 / 64, 768 / 64),  256, 0, stream>>>(qkv_w, qkvT, 768, 2304);
    wconv_kernel<<<dim3(768 / 64,  768 / 64),  256, 0, stream>>>(proj_w, projT, 768, 768);
    wconv_kernel<<<dim3(3072 / 64, 768 / 64),  256, 0, stream>>>(fc1_w, fc1T, 768, 3072);
    wconv_kernel<<<dim3(768 / 64,  3072 / 64), 256, 0, stream>>>(fc2_w, fc2T, 3072, 768);

    ln_kernel<<<ROWS, 256, 0, stream>>>(x, ln1_g, ln1_b, h);
    gemm_bf16<0><<<dim3(2304 / 128, 32), 256, 0, stream>>>(
        h, qkvT, qkv_b, nullptr, nullptr, nullptr, qb, kb, vb, 2304, 768);
    attn_mfma<<<dim3(32, HEADS, 2), 256, 0, stream>>>(qb, kb, vb, elev, barrier, attn);
    gemm_bf16<2><<<dim3(768 / 128, 32), 256, 0, stream>>>(
        attn, projT, proj_b, x, out, nullptr, nullptr, nullptr, nullptr, 768, 768);
    ln_kernel<<<ROWS, 256, 0, stream>>>(out, ln2_g, ln2_b, h2);
    gemm_bf16<1><<<dim3(3072 / 128, 32), 256, 0, stream>>>(
        h2, fc1T, fc1_b, nullptr, nullptr, f1, nullptr, nullptr, nullptr, 3072, 768);
    gemm_bf16<2><<<dim3(768 / 128, 32), 256, 0, stream>>>(
        f1, fc2T, fc2_b, out, out, nullptr, nullptr, nullptr, nullptr, 768, 3072);
}

// Round 3
// 368.103 us; speedup vs baseline: 5.3275x; 1.2682x over previous
//
#include <hip/hip_runtime.h>
#include <math.h>

#define DIM 768
#define HEADS 12
#define SEQ 2048
#define ROWS 4096
#define LN_EPS 1e-5f

typedef __attribute__((ext_vector_type(8))) short short8;
typedef __attribute__((ext_vector_type(4))) float floatx4;
typedef unsigned short ushort_t;

__device__ __forceinline__ ushort_t f2bf(float x) {
    unsigned u = __float_as_uint(x);
    u += 0x7fff + ((u >> 16) & 1);
    return (ushort_t)(u >> 16);
}

__device__ __forceinline__ void gload_lds16(const void* g, void* l) {
    __builtin_amdgcn_global_load_lds((const __attribute__((address_space(1))) void*)g,
                                     (__attribute__((address_space(3))) void*)l, 16, 0, 0);
}

// ---------- weight convert + transpose: W[K][N] fp32 -> WT[N][K] bf16 ----------
__launch_bounds__(256)
__global__ void wconv_kernel(const float* __restrict__ W, ushort_t* __restrict__ WT,
                             int K, int N) {
    __shared__ __align__(16) ushort_t s[64][72];
    int k0 = blockIdx.y * 64, n0 = blockIdx.x * 64;
    int t = threadIdx.x;
    int rr0 = t >> 4, c4 = (t & 15) * 4;
    for (int rr = rr0; rr < 64; rr += 16) {
        float4 w = *(const float4*)(W + (size_t)(k0 + rr) * N + n0 + c4);
        s[c4 + 0][rr] = f2bf(w.x); s[c4 + 1][rr] = f2bf(w.y);
        s[c4 + 2][rr] = f2bf(w.z); s[c4 + 3][rr] = f2bf(w.w);
    }
    __syncthreads();
    int nl = t >> 2, kq = (t & 3) * 16;
    uint4 a = *(const uint4*)&s[nl][kq];
    uint4 b = *(const uint4*)&s[nl][kq + 8];
    *(uint4*)(WT + (size_t)(n0 + nl) * K + k0 + kq) = a;
    *(uint4*)(WT + (size_t)(n0 + nl) * K + k0 + kq + 8) = b;
}

// ---------- elevation mask factors: G=exp(b*e), iG=exp(-b*e), C2=b*e ----------
__launch_bounds__(256)
__global__ void gelev_kernel(const float* __restrict__ elev, const float* __restrict__ barrier_p,
                             float* __restrict__ G, float* __restrict__ iG,
                             float* __restrict__ C2) {
    int i = blockIdx.x * 256 + threadIdx.x;
    float be = barrier_p[0] * elev[i];
    G[i]  = __expf(be);
    iG[i] = __expf(-be);
    C2[i] = be;
}

// ---------- LayerNorm fp32 in -> bf16 out ----------
__launch_bounds__(256)
__global__ void ln_kernel(const float* __restrict__ x, const float* __restrict__ g,
                          const float* __restrict__ b, ushort_t* __restrict__ out) {
    int row = blockIdx.x;
    const float* xr = x + (size_t)row * DIM;
    int t = threadIdx.x;
    float v0 = xr[t], v1 = xr[t + 256], v2 = xr[t + 512];
    float s  = v0 + v1 + v2;
    float ss = v0 * v0 + v1 * v1 + v2 * v2;
    #pragma unroll
    for (int o = 32; o >= 1; o >>= 1) { s += __shfl_xor(s, o); ss += __shfl_xor(ss, o); }
    __shared__ float rs[4], rss[4];
    int wid = t >> 6, lane = t & 63;
    if (lane == 0) { rs[wid] = s; rss[wid] = ss; }
    __syncthreads();
    if (t == 0) {
        float S = 0.f, SS = 0.f;
        for (int i = 0; i < 4; i++) { S += rs[i]; SS += rss[i]; }
        rs[0] = S; rss[0] = SS;
    }
    __syncthreads();
    float mean = rs[0] * (1.0f / DIM);
    float var  = rss[0] * (1.0f / DIM) - mean * mean;
    float rstd = rsqrtf(var + LN_EPS);
    ushort_t* orow = out + (size_t)row * DIM;
    orow[t]       = f2bf((v0 - mean) * rstd * g[t]       + b[t]);
    orow[t + 256] = f2bf((v1 - mean) * rstd * g[t + 256] + b[t + 256]);
    orow[t + 512] = f2bf((v2 - mean) * rstd * g[t + 512] + b[t + 512]);
}

// ---------- bf16 MFMA GEMM: C = A[M,K] @ WT[N,K]^T + bias ----------
// EPI 0: qkv special (q scaled by 0.125 & row-major, k row-major, v transposed)
// EPI 1: gelu -> bf16 row-major   EPI 2: + res(fp32) -> fp32
template<int EPI>
__launch_bounds__(256)
__global__ void gemm_bf16(const ushort_t* __restrict__ A, const ushort_t* __restrict__ WT,
                          const float* __restrict__ bias, const float* __restrict__ res,
                          float* __restrict__ outF, ushort_t* __restrict__ outB,
                          ushort_t* __restrict__ qb, ushort_t* __restrict__ kb,
                          ushort_t* __restrict__ vb, int N, int K) {
    __shared__ __align__(16) ushort_t sA[128 * 32];
    __shared__ __align__(16) ushort_t sB[128 * 32];
    int t = threadIdx.x;
    int row0 = blockIdx.y * 128, col0 = blockIdx.x * 128;
    int wid = t >> 6, lane = t & 63;
    int wm = wid >> 1, wn = wid & 1;
    int cl = lane & 15, quad = lane >> 4;

    floatx4 acc[4][4];
    #pragma unroll
    for (int i = 0; i < 4; i++)
        #pragma unroll
        for (int j = 0; j < 4; j++) { floatx4 z = {0.f, 0.f, 0.f, 0.f}; acc[i][j] = z; }

    for (int k0 = 0; k0 < K; k0 += 32) {
        #pragma unroll
        for (int i = 0; i < 2; i++) {
            int c = i * 256 + t;
            int r = c >> 2, sub = c & 3;
            gload_lds16(A  + (size_t)(row0 + r) * K + k0 + sub * 8, &sA[c * 8]);
            gload_lds16(WT + (size_t)(col0 + r) * K + k0 + sub * 8, &sB[c * 8]);
        }
        __syncthreads();
        short8 a[4], b[4];
        #pragma unroll
        for (int i = 0; i < 4; i++)
            a[i] = *(const short8*)&sA[(wm * 64 + i * 16 + cl) * 32 + quad * 8];
        #pragma unroll
        for (int j = 0; j < 4; j++)
            b[j] = *(const short8*)&sB[(wn * 64 + j * 16 + cl) * 32 + quad * 8];
        #pragma unroll
        for (int i = 0; i < 4; i++)
            #pragma unroll
            for (int j = 0; j < 4; j++)
                acc[i][j] = __builtin_amdgcn_mfma_f32_16x16x32_bf16(a[i], b[j], acc[i][j], 0, 0, 0);
        __syncthreads();
    }

    #pragma unroll
    for (int i = 0; i < 4; i++) {
        #pragma unroll
        for (int j = 0; j < 4; j++) {
            int gcol = col0 + wn * 64 + j * 16 + cl;
            float bv = bias[gcol];
            #pragma unroll
            for (int rg = 0; rg < 4; rg++) {
                int grow = row0 + wm * 64 + i * 16 + quad * 4 + rg;
                float v = acc[i][j][rg] + bv;
                if (EPI == 0) {
                    int which = gcol / 768;
                    int hc = gcol - which * 768;
                    int h = hc >> 6, d = hc & 63;
                    int b_ = grow >> 11, n = grow & 2047;
                    size_t bh = (size_t)(b_ * 12 + h);
                    if (which == 0)      qb[(bh * 2048 + n) * 64 + d] = f2bf(v * 0.125f);
                    else if (which == 1) kb[(bh * 2048 + n) * 64 + d] = f2bf(v);
                    else                 vb[(bh * 64 + d) * 2048 + n] = f2bf(v);
                } else if (EPI == 1) {
                    v = 0.5f * v * (1.f + erff(v * 0.70710678118654752f));
                    outB[(size_t)grow * N + gcol] = f2bf(v);
                } else {
                    v += res[(size_t)grow * N + gcol];
                    outF[(size_t)grow * N + gcol] = v;
                }
            }
        }
    }
}

// ---------- MFMA flash attention, no online max, folded mask ----------
// t = exp(q.k/8 + b*ej) (Q pre-scaled, b*ej in acc-init); e = t*iGj; p = t/(Gi+Gj)
// out = sum(p*v) / (sum(p) + 1e-8*sum(e))   [== reference identity]
__launch_bounds__(256)
__global__ void attn_mfma(const ushort_t* __restrict__ qb, const ushort_t* __restrict__ kb,
                          const ushort_t* __restrict__ vb, const float* __restrict__ G,
                          const float* __restrict__ iG, const float* __restrict__ C2,
                          ushort_t* __restrict__ attn) {
    __shared__ __align__(16) ushort_t Qs[64 * 64];
    __shared__ __align__(16) ushort_t Ks[64 * 64];
    __shared__ __align__(16) ushort_t Vt[64 * 64];
    __shared__ __align__(16) ushort_t Ps[64 * 64];
    __shared__ float Gjs[64], iGjs[64], C2s[64];
    int qt = blockIdx.x, h = blockIdx.y, b = blockIdx.z;
    int t = threadIdx.x, wid = t >> 6, lane = t & 63;
    int cl = lane & 15, quad = lane >> 4;
    int q0 = qt * 64;
    size_t bh = (size_t)(b * 12 + h);

    // stage Q, XOR-swizzled (blk ^= row&7) via permuted glds SOURCE addresses
    const ushort_t* qbase = qb + (bh * 2048 + q0) * 64;
    #pragma unroll
    for (int i = 0; i < 2; i++) {
        int c = i * 256 + t, row = c >> 3, blk = c & 7;
        gload_lds16(qbase + (row << 6) + ((blk ^ (row & 7)) << 3), &Qs[c * 8]);
    }
    float gi[4];
    #pragma unroll
    for (int rg = 0; rg < 4; rg++)
        gi[rg] = G[(size_t)b * 2048 + q0 + wid * 16 + quad * 4 + rg];

    floatx4 o[4];
    #pragma unroll
    for (int j = 0; j < 4; j++) { floatx4 z = {0.f, 0.f, 0.f, 0.f}; o[j] = z; }
    float se[4] = {0.f, 0.f, 0.f, 0.f}, sem[4] = {0.f, 0.f, 0.f, 0.f};

    for (int kt = 0; kt < 32; kt++) {
        int k0 = kt * 64;
        const ushort_t* kbase = kb + (bh * 2048 + k0) * 64;
        const ushort_t* vbase = vb + bh * 131072 + k0;
        #pragma unroll
        for (int i = 0; i < 2; i++) {
            int c = i * 256 + t, row = c >> 3, blk = c & 7;
            gload_lds16(kbase + (row << 6) + ((blk ^ (row & 7)) << 3), &Ks[c * 8]);
            gload_lds16(vbase + (size_t)row * 2048 + ((blk ^ (row & 7)) << 3), &Vt[c * 8]);
        }
        if (t < 64) {
            int gidx = b * 2048 + k0 + t;
            Gjs[t] = G[gidx]; iGjs[t] = iG[gidx]; C2s[t] = C2[gidx];
        }
        __syncthreads();

        float c2v[4], gjv[4], igv[4];
        #pragma unroll
        for (int nt = 0; nt < 4; nt++) {
            int j = nt * 16 + cl;
            c2v[nt] = C2s[j]; gjv[nt] = Gjs[j]; igv[nt] = iGjs[j];
        }

        // S = Q K^T with acc pre-init to barrier*ej (column value)
        floatx4 s[4];
        #pragma unroll
        for (int nt = 0; nt < 4; nt++) {
            floatx4 z = {c2v[nt], c2v[nt], c2v[nt], c2v[nt]};
            s[nt] = z;
        }
        #pragma unroll
        for (int kh = 0; kh < 2; kh++) {
            short8 aq = *(const short8*)&Qs[((wid * 16 + cl) << 6) + (((kh * 4 + quad) ^ (cl & 7)) << 3)];
            #pragma unroll
            for (int nt = 0; nt < 4; nt++) {
                short8 bk = *(const short8*)&Ks[((nt * 16 + cl) << 6) + (((kh * 4 + quad) ^ (cl & 7)) << 3)];
                s[nt] = __builtin_amdgcn_mfma_f32_16x16x32_bf16(aq, bk, s[nt], 0, 0, 0);
            }
        }

        // softmax numerators + mask, write P (bf16 trunc) swizzled
        #pragma unroll
        for (int rg = 0; rg < 4; rg++) {
            int prow = wid * 16 + quad * 4 + rg;
            int r8 = prow & 7;
            #pragma unroll
            for (int nt = 0; nt < 4; nt++) {
                float tf = __expf(s[nt][rg]);
                float R  = __builtin_amdgcn_rcpf(gi[rg] + gjv[nt]);
                float e  = tf * igv[nt];
                float p  = tf * R;
                se[rg]  += e;
                sem[rg] += p;
                int addr = (prow << 6) + ((((nt * 2) + (cl >> 3)) ^ r8) << 3) + (cl & 7);
                Ps[addr] = (ushort_t)(__float_as_uint(p) >> 16);
            }
        }

        // O += P V
        #pragma unroll
        for (int kh = 0; kh < 2; kh++) {
            short8 ap = *(const short8*)&Ps[((wid * 16 + cl) << 6) + (((kh * 4 + quad) ^ (cl & 7)) << 3)];
            #pragma unroll
            for (int dt = 0; dt < 4; dt++) {
                short8 bv = *(const short8*)&Vt[((dt * 16 + cl) << 6) + (((kh * 4 + quad) ^ (cl & 7)) << 3)];
                o[dt] = __builtin_amdgcn_mfma_f32_16x16x32_bf16(ap, bv, o[dt], 0, 0, 0);
            }
        }
        __syncthreads();
    }

    #pragma unroll
    for (int rg = 0; rg < 4; rg++) {
        float a = se[rg], m = sem[rg];
        #pragma unroll
        for (int off = 1; off < 16; off <<= 1) { a += __shfl_xor(a, off); m += __shfl_xor(m, off); }
        float inv = __builtin_amdgcn_rcpf(m + 1e-8f * a);
        int grow = b * 2048 + q0 + wid * 16 + quad * 4 + rg;
        #pragma unroll
        for (int dt = 0; dt < 4; dt++)
            attn[(size_t)grow * 768 + h * 64 + dt * 16 + cl] = f2bf(o[dt][rg] * inv);
    }
}

extern "C" void kernel_launch(void* const* d_in, const int* in_sizes, int n_in,
                              void* d_out, int out_size, void* d_ws, size_t ws_size,
                              hipStream_t stream) {
    const float* x      = (const float*)d_in[0];
    const float* elev   = (const float*)d_in[1];
    const float* qkv_w  = (const float*)d_in[2];
    const float* qkv_b  = (const float*)d_in[3];
    const float* proj_w = (const float*)d_in[4];
    const float* proj_b = (const float*)d_in[5];
    const float* ln1_g  = (const float*)d_in[6];
    const float* ln1_b  = (const float*)d_in[7];
    const float* ln2_g  = (const float*)d_in[8];
    const float* ln2_b  = (const float*)d_in[9];
    const float* fc1_w  = (const float*)d_in[10];
    const float* fc1_b  = (const float*)d_in[11];
    const float* fc2_w  = (const float*)d_in[12];
    const float* fc2_b  = (const float*)d_in[13];
    const float* barrier= (const float*)d_in[14];
    float* out = (float*)d_out;
    char* ws = (char*)d_ws;

    ushort_t* h    = (ushort_t*)(ws + 0);         // 6291456 B
    ushort_t* qb   = (ushort_t*)(ws + 6291456);   // 6291456
    ushort_t* kb   = (ushort_t*)(ws + 12582912);  // 6291456
    ushort_t* vb   = (ushort_t*)(ws + 18874368);  // 6291456
    ushort_t* f1   = (ushort_t*)(ws + 0);         // 25165824 (overlays h,qb,kb,vb; written after attn)
    ushort_t* attn = (ushort_t*)(ws + 25165824);  // 6291456
    ushort_t* h2   = (ushort_t*)(ws + 31457280);  // 6291456 (written by ln2 AFTER attn)
    // G/iG/C2 (48 KB) overlay the h2 region — dead before ln2 writes h2
    float*    Gf   = (float*)(ws + 31457280);
    float*    iGf  = (float*)(ws + 31473664);
    float*    C2f  = (float*)(ws + 31490048);
    ushort_t* qkvT = (ushort_t*)(ws + 37748736);  // 3538944
    ushort_t* projT= (ushort_t*)(ws + 41287680);  // 1179648
    ushort_t* fc1T = (ushort_t*)(ws + 42467328);  // 4718592
    ushort_t* fc2T = (ushort_t*)(ws + 47185920);  // 4718592

    wconv_kernel<<<dim3(2304 / 64, 768 / 64),  256, 0, stream>>>(qkv_w, qkvT, 768, 2304);
    wconv_kernel<<<dim3(768 / 64,  768 / 64),  256, 0, stream>>>(proj_w, projT, 768, 768);
    wconv_kernel<<<dim3(3072 / 64, 768 / 64),  256, 0, stream>>>(fc1_w, fc1T, 768, 3072);
    wconv_kernel<<<dim3(768 / 64,  3072 / 64), 256, 0, stream>>>(fc2_w, fc2T, 3072, 768);
    gelev_kernel<<<16, 256, 0, stream>>>(elev, barrier, Gf, iGf, C2f);

    ln_kernel<<<ROWS, 256, 0, stream>>>(x, ln1_g, ln1_b, h);
    gemm_bf16<0><<<dim3(2304 / 128, 32), 256, 0, stream>>>(
        h, qkvT, qkv_b, nullptr, nullptr, nullptr, qb, kb, vb, 2304, 768);
    attn_mfma<<<dim3(32, HEADS, 2), 256, 0, stream>>>(qb, kb, vb, Gf, iGf, C2f, attn);
    gemm_bf16<2><<<dim3(768 / 128, 32), 256, 0, stream>>>(
        attn, projT, proj_b, x, out, nullptr, nullptr, nullptr, nullptr, 768, 768);
    ln_kernel<<<ROWS, 256, 0, stream>>>(out, ln2_g, ln2_b, h2);
    gemm_bf16<1><<<dim3(3072 / 128, 32), 256, 0, stream>>>(
        h2, fc1T, fc1_b, nullptr, nullptr, f1, nullptr, nullptr, nullptr, 3072, 768);
    gemm_bf16<2><<<dim3(768 / 128, 32), 256, 0, stream>>>(
        f1, fc2T, fc2_b, out, out, nullptr, nullptr, nullptr, nullptr, 768, 3072);
}

// Round 4
// 352.865 us; speedup vs baseline: 5.5576x; 1.0432x over previous
//
#include <hip/hip_runtime.h>
#include <math.h>

#define DIM 768
#define HEADS 12
#define SEQ 2048
#define ROWS 4096
#define LN_EPS 1e-5f

typedef __attribute__((ext_vector_type(8))) short short8;
typedef __attribute__((ext_vector_type(4))) float floatx4;
typedef unsigned short ushort_t;

__device__ __forceinline__ ushort_t f2bf(float x) {
    unsigned u = __float_as_uint(x);
    u += 0x7fff + ((u >> 16) & 1);
    return (ushort_t)(u >> 16);
}

__device__ __forceinline__ void gload_lds16(const void* g, void* l) {
    __builtin_amdgcn_global_load_lds((const __attribute__((address_space(1))) void*)g,
                                     (__attribute__((address_space(3))) void*)l, 16, 0, 0);
}

// ---------- weight convert + transpose: W[K][N] fp32 -> WT[N][K] bf16 ----------
__launch_bounds__(256)
__global__ void wconv_kernel(const float* __restrict__ W, ushort_t* __restrict__ WT,
                             int K, int N) {
    __shared__ __align__(16) ushort_t s[64][72];
    int k0 = blockIdx.y * 64, n0 = blockIdx.x * 64;
    int t = threadIdx.x;
    int rr0 = t >> 4, c4 = (t & 15) * 4;
    for (int rr = rr0; rr < 64; rr += 16) {
        float4 w = *(const float4*)(W + (size_t)(k0 + rr) * N + n0 + c4);
        s[c4 + 0][rr] = f2bf(w.x); s[c4 + 1][rr] = f2bf(w.y);
        s[c4 + 2][rr] = f2bf(w.z); s[c4 + 3][rr] = f2bf(w.w);
    }
    __syncthreads();
    int nl = t >> 2, kq = (t & 3) * 16;
    uint4 a = *(const uint4*)&s[nl][kq];
    uint4 b = *(const uint4*)&s[nl][kq + 8];
    *(uint4*)(WT + (size_t)(n0 + nl) * K + k0 + kq) = a;
    *(uint4*)(WT + (size_t)(n0 + nl) * K + k0 + kq + 8) = b;
}

// ---------- elevation mask factors ----------
__launch_bounds__(256)
__global__ void gelev_kernel(const float* __restrict__ elev, const float* __restrict__ barrier_p,
                             float* __restrict__ G, float* __restrict__ iG,
                             float* __restrict__ C2) {
    int i = blockIdx.x * 256 + threadIdx.x;
    float be = barrier_p[0] * elev[i];
    G[i]  = __expf(be);
    iG[i] = __expf(-be);
    C2[i] = be;
}

// ---------- LayerNorm fp32 in -> bf16 out ----------
__launch_bounds__(256)
__global__ void ln_kernel(const float* __restrict__ x, const float* __restrict__ g,
                          const float* __restrict__ b, ushort_t* __restrict__ out) {
    int row = blockIdx.x;
    const float* xr = x + (size_t)row * DIM;
    int t = threadIdx.x;
    float v0 = xr[t], v1 = xr[t + 256], v2 = xr[t + 512];
    float s  = v0 + v1 + v2;
    float ss = v0 * v0 + v1 * v1 + v2 * v2;
    #pragma unroll
    for (int o = 32; o >= 1; o >>= 1) { s += __shfl_xor(s, o); ss += __shfl_xor(ss, o); }
    __shared__ float rs[4], rss[4];
    int wid = t >> 6, lane = t & 63;
    if (lane == 0) { rs[wid] = s; rss[wid] = ss; }
    __syncthreads();
    if (t == 0) {
        float S = 0.f, SS = 0.f;
        for (int i = 0; i < 4; i++) { S += rs[i]; SS += rss[i]; }
        rs[0] = S; rss[0] = SS;
    }
    __syncthreads();
    float mean = rs[0] * (1.0f / DIM);
    float var  = rss[0] * (1.0f / DIM) - mean * mean;
    float rstd = rsqrtf(var + LN_EPS);
    ushort_t* orow = out + (size_t)row * DIM;
    orow[t]       = f2bf((v0 - mean) * rstd * g[t]       + b[t]);
    orow[t + 256] = f2bf((v1 - mean) * rstd * g[t + 256] + b[t + 256]);
    orow[t + 512] = f2bf((v2 - mean) * rstd * g[t + 512] + b[t + 512]);
}

// ---------- bf16 MFMA GEMM: C = A[M,K] @ WT[N,K]^T + bias, BM=64 tiles ----------
// EPI 0: qkv special   EPI 1: gelu -> bf16   EPI 2: + res(fp32) -> fp32
template<int BN, int EPI>
__launch_bounds__(256)
__global__ void gemm_bf16(const ushort_t* __restrict__ A, const ushort_t* __restrict__ WT,
                          const float* __restrict__ bias, const float* __restrict__ res,
                          float* __restrict__ outF, ushort_t* __restrict__ outB,
                          ushort_t* __restrict__ qb, ushort_t* __restrict__ kb,
                          ushort_t* __restrict__ vb, int N, int K) {
    constexpr int NT = BN / 32;          // n-tiles per wave
    __shared__ __align__(16) ushort_t sA[64 * 32];
    __shared__ __align__(16) ushort_t sB[BN * 32];
    int t = threadIdx.x;
    int row0 = blockIdx.y * 64, col0 = blockIdx.x * BN;
    int wid = t >> 6, lane = t & 63;
    int wm = wid >> 1, wn = wid & 1;
    int cl = lane & 15, quad = lane >> 4;

    floatx4 acc[2][NT];
    #pragma unroll
    for (int i = 0; i < 2; i++)
        #pragma unroll
        for (int j = 0; j < NT; j++) { floatx4 z = {0.f, 0.f, 0.f, 0.f}; acc[i][j] = z; }

    for (int k0 = 0; k0 < K; k0 += 32) {
        {   // A tile 64x32: 1 load/thread
            int r = t >> 2, sub = t & 3;
            gload_lds16(A + (size_t)(row0 + r) * K + k0 + sub * 8, &sA[t * 8]);
        }
        #pragma unroll
        for (int i = 0; i < BN / 64; i++) {   // B tile BNx32
            int c = i * 256 + t;
            int r = c >> 2, sub = c & 3;
            gload_lds16(WT + (size_t)(col0 + r) * K + k0 + sub * 8, &sB[c * 8]);
        }
        __syncthreads();
        short8 a[2], b[NT];
        #pragma unroll
        for (int i = 0; i < 2; i++)
            a[i] = *(const short8*)&sA[(wm * 32 + i * 16 + cl) * 32 + quad * 8];
        #pragma unroll
        for (int j = 0; j < NT; j++)
            b[j] = *(const short8*)&sB[(wn * (BN / 2) + j * 16 + cl) * 32 + quad * 8];
        #pragma unroll
        for (int i = 0; i < 2; i++)
            #pragma unroll
            for (int j = 0; j < NT; j++)
                acc[i][j] = __builtin_amdgcn_mfma_f32_16x16x32_bf16(a[i], b[j], acc[i][j], 0, 0, 0);
        __syncthreads();
    }

    #pragma unroll
    for (int i = 0; i < 2; i++) {
        #pragma unroll
        for (int j = 0; j < NT; j++) {
            int gcol = col0 + wn * (BN / 2) + j * 16 + cl;
            float bv = bias[gcol];
            #pragma unroll
            for (int rg = 0; rg < 4; rg++) {
                int grow = row0 + wm * 32 + i * 16 + quad * 4 + rg;
                float v = acc[i][j][rg] + bv;
                if (EPI == 0) {
                    int which = gcol / 768;
                    int hc = gcol - which * 768;
                    int h = hc >> 6, d = hc & 63;
                    int b_ = grow >> 11, n = grow & 2047;
                    size_t bh = (size_t)(b_ * 12 + h);
                    if (which == 0)      qb[(bh * 2048 + n) * 64 + d] = f2bf(v * 0.125f);
                    else if (which == 1) kb[(bh * 2048 + n) * 64 + d] = f2bf(v);
                    else                 vb[(bh * 64 + d) * 2048 + n] = f2bf(v);
                } else if (EPI == 1) {
                    v = 0.5f * v * (1.f + erff(v * 0.70710678118654752f));
                    outB[(size_t)grow * N + gcol] = f2bf(v);
                } else {
                    v += res[(size_t)grow * N + gcol];
                    outF[(size_t)grow * N + gcol] = v;
                }
            }
        }
    }
}

// ---------- MFMA flash attention, double-buffered K/V, row-folded mask ----------
// t = exp(q.k/8 + b*ei) (Q pre-scaled, b*ei in acc-init, per-row)
// p = t/(Gi+Gj) = exp(s)*sigmoid(b*(ei-ej))  [the reference mask exactly]
// e = t*iGi -> folded: sum_e = iGi * sum_t
// out = sum(p*v) / (sum_p + 1e-8*sum_e)
__launch_bounds__(256)
__global__ void attn_mfma(const ushort_t* __restrict__ qb, const ushort_t* __restrict__ kb,
                          const ushort_t* __restrict__ vb, const float* __restrict__ G,
                          const float* __restrict__ iG, const float* __restrict__ C2,
                          ushort_t* __restrict__ attn) {
    __shared__ __align__(16) ushort_t Qs[64 * 64];
    __shared__ __align__(16) ushort_t Ks[2][64 * 64];
    __shared__ __align__(16) ushort_t Vt[2][64 * 64];
    __shared__ __align__(16) ushort_t Ps[64 * 64];
    __shared__ float Gjs[2][64];
    int qt = blockIdx.x, h = blockIdx.y, b = blockIdx.z;
    int t = threadIdx.x, wid = t >> 6, lane = t & 63;
    int cl = lane & 15, quad = lane >> 4;
    int q0 = qt * 64;
    size_t bh = (size_t)(b * 12 + h);

    // stage Q, XOR-swizzled via permuted glds SOURCE addresses
    const ushort_t* qbase = qb + (bh * 2048 + q0) * 64;
    #pragma unroll
    for (int i = 0; i < 2; i++) {
        int c = i * 256 + t, row = c >> 3, blk = c & 7;
        gload_lds16(qbase + (row << 6) + ((blk ^ (row & 7)) << 3), &Qs[c * 8]);
    }
    // per-row mask params (4 consecutive rows per thread)
    int qrow = b * 2048 + q0 + wid * 16 + quad * 4;
    float4 g4  = *(const float4*)(G  + qrow);
    float4 ig4 = *(const float4*)(iG + qrow);
    float4 c24 = *(const float4*)(C2 + qrow);
    float gi[4]  = {g4.x, g4.y, g4.z, g4.w};
    float igi[4] = {ig4.x, ig4.y, ig4.z, ig4.w};
    floatx4 c2init = {c24.x, c24.y, c24.z, c24.w};

    // prefetch tile 0
    {
        const ushort_t* kbase = kb + bh * 2048 * 64;
        const ushort_t* vbase = vb + bh * 131072;
        #pragma unroll
        for (int i = 0; i < 2; i++) {
            int c = i * 256 + t, row = c >> 3, blk = c & 7;
            gload_lds16(kbase + (row << 6) + ((blk ^ (row & 7)) << 3), &Ks[0][c * 8]);
            gload_lds16(vbase + (size_t)row * 2048 + ((blk ^ (row & 7)) << 3), &Vt[0][c * 8]);
        }
        if (t < 64) Gjs[0][t] = G[b * 2048 + t];
    }

    floatx4 o[4];
    #pragma unroll
    for (int j = 0; j < 4; j++) { floatx4 z = {0.f, 0.f, 0.f, 0.f}; o[j] = z; }
    float se[4] = {0.f, 0.f, 0.f, 0.f}, sem[4] = {0.f, 0.f, 0.f, 0.f};

    for (int kt = 0; kt < 32; kt++) {
        int cur = kt & 1;
        __syncthreads();   // drains prefetch(kt); guards buf cur^1 reuse
        if (kt < 31) {     // prefetch kt+1 into the other buffer (overlaps compute)
            int k0n = (kt + 1) * 64;
            const ushort_t* kbase = kb + (bh * 2048 + k0n) * 64;
            const ushort_t* vbase = vb + bh * 131072 + k0n;
            #pragma unroll
            for (int i = 0; i < 2; i++) {
                int c = i * 256 + t, row = c >> 3, blk = c & 7;
                gload_lds16(kbase + (row << 6) + ((blk ^ (row & 7)) << 3), &Ks[cur ^ 1][c * 8]);
                gload_lds16(vbase + (size_t)row * 2048 + ((blk ^ (row & 7)) << 3), &Vt[cur ^ 1][c * 8]);
            }
            if (t < 64) Gjs[cur ^ 1][t] = G[b * 2048 + k0n + t];
        }

        float gjv[4];
        #pragma unroll
        for (int nt = 0; nt < 4; nt++) gjv[nt] = Gjs[cur][nt * 16 + cl];

        // S = Q K^T, acc pre-init = barrier*ei (row value)
        floatx4 s[4];
        #pragma unroll
        for (int nt = 0; nt < 4; nt++) s[nt] = c2init;
        #pragma unroll
        for (int kh = 0; kh < 2; kh++) {
            short8 aq = *(const short8*)&Qs[((wid * 16 + cl) << 6) + (((kh * 4 + quad) ^ (cl & 7)) << 3)];
            #pragma unroll
            for (int nt = 0; nt < 4; nt++) {
                short8 bk = *(const short8*)&Ks[cur][((nt * 16 + cl) << 6) + (((kh * 4 + quad) ^ (cl & 7)) << 3)];
                s[nt] = __builtin_amdgcn_mfma_f32_16x16x32_bf16(aq, bk, s[nt], 0, 0, 0);
            }
        }

        // softmax numerators + mask, write P swizzled
        #pragma unroll
        for (int rg = 0; rg < 4; rg++) {
            int prow = wid * 16 + quad * 4 + rg;
            int r8 = prow & 7, pbase = prow << 6, csub = cl & 7, chi = cl >> 3;
            #pragma unroll
            for (int nt = 0; nt < 4; nt++) {
                float tf = __expf(s[nt][rg]);
                float R  = __builtin_amdgcn_rcpf(gi[rg] + gjv[nt]);
                float p  = tf * R;
                se[rg]  += tf;
                sem[rg] += p;
                Ps[pbase + (((nt * 2 + chi) ^ r8) << 3) + csub] = (ushort_t)(__float_as_uint(p) >> 16);
            }
        }

        // O += P V
        #pragma unroll
        for (int kh = 0; kh < 2; kh++) {
            short8 ap = *(const short8*)&Ps[((wid * 16 + cl) << 6) + (((kh * 4 + quad) ^ (cl & 7)) << 3)];
            #pragma unroll
            for (int dt = 0; dt < 4; dt++) {
                short8 bv = *(const short8*)&Vt[cur][((dt * 16 + cl) << 6) + (((kh * 4 + quad) ^ (cl & 7)) << 3)];
                o[dt] = __builtin_amdgcn_mfma_f32_16x16x32_bf16(ap, bv, o[dt], 0, 0, 0);
            }
        }
    }

    #pragma unroll
    for (int rg = 0; rg < 4; rg++) {
        float a = se[rg], m = sem[rg];
        #pragma unroll
        for (int off = 1; off < 16; off <<= 1) { a += __shfl_xor(a, off); m += __shfl_xor(m, off); }
        float inv = __builtin_amdgcn_rcpf(m + 1e-8f * a * igi[rg]);
        int grow = b * 2048 + q0 + wid * 16 + quad * 4 + rg;
        #pragma unroll
        for (int dt = 0; dt < 4; dt++)
            attn[(size_t)grow * 768 + h * 64 + dt * 16 + cl] = f2bf(o[dt][rg] * inv);
    }
}

extern "C" void kernel_launch(void* const* d_in, const int* in_sizes, int n_in,
                              void* d_out, int out_size, void* d_ws, size_t ws_size,
                              hipStream_t stream) {
    const float* x      = (const float*)d_in[0];
    const float* elev   = (const float*)d_in[1];
    const float* qkv_w  = (const float*)d_in[2];
    const float* qkv_b  = (const float*)d_in[3];
    const float* proj_w = (const float*)d_in[4];
    const float* proj_b = (const float*)d_in[5];
    const float* ln1_g  = (const float*)d_in[6];
    const float* ln1_b  = (const float*)d_in[7];
    const float* ln2_g  = (const float*)d_in[8];
    const float* ln2_b  = (const float*)d_in[9];
    const float* fc1_w  = (const float*)d_in[10];
    const float* fc1_b  = (const float*)d_in[11];
    const float* fc2_w  = (const float*)d_in[12];
    const float* fc2_b  = (const float*)d_in[13];
    const float* barrier= (const float*)d_in[14];
    float* out = (float*)d_out;
    char* ws = (char*)d_ws;

    ushort_t* h    = (ushort_t*)(ws + 0);         // 6291456 B
    ushort_t* qb   = (ushort_t*)(ws + 6291456);   // 6291456
    ushort_t* kb   = (ushort_t*)(ws + 12582912);  // 6291456
    ushort_t* vb   = (ushort_t*)(ws + 18874368);  // 6291456
    ushort_t* f1   = (ushort_t*)(ws + 0);         // 25165824 (overlays h,qb,kb,vb)
    ushort_t* attn = (ushort_t*)(ws + 25165824);  // 6291456
    ushort_t* h2   = (ushort_t*)(ws + 31457280);  // 6291456
    float*    Gf   = (float*)(ws + 31457280);     // overlay h2 region, dead before ln2
    float*    iGf  = (float*)(ws + 31473664);
    float*    C2f  = (float*)(ws + 31490048);
    ushort_t* qkvT = (ushort_t*)(ws + 37748736);  // 3538944
    ushort_t* projT= (ushort_t*)(ws + 41287680);  // 1179648
    ushort_t* fc1T = (ushort_t*)(ws + 42467328);  // 4718592
    ushort_t* fc2T = (ushort_t*)(ws + 47185920);  // 4718592

    wconv_kernel<<<dim3(2304 / 64, 768 / 64),  256, 0, stream>>>(qkv_w, qkvT, 768, 2304);
    wconv_kernel<<<dim3(768 / 64,  768 / 64),  256, 0, stream>>>(proj_w, projT, 768, 768);
    wconv_kernel<<<dim3(3072 / 64, 768 / 64),  256, 0, stream>>>(fc1_w, fc1T, 768, 3072);
    wconv_kernel<<<dim3(768 / 64,  3072 / 64), 256, 0, stream>>>(fc2_w, fc2T, 3072, 768);
    gelev_kernel<<<16, 256, 0, stream>>>(elev, barrier, Gf, iGf, C2f);

    ln_kernel<<<ROWS, 256, 0, stream>>>(x, ln1_g, ln1_b, h);
    gemm_bf16<128, 0><<<dim3(2304 / 128, 64), 256, 0, stream>>>(
        h, qkvT, qkv_b, nullptr, nullptr, nullptr, qb, kb, vb, 2304, 768);
    attn_mfma<<<dim3(32, HEADS, 2), 256, 0, stream>>>(qb, kb, vb, Gf, iGf, C2f, attn);
    gemm_bf16<64, 2><<<dim3(768 / 64, 64), 256, 0, stream>>>(
        attn, projT, proj_b, x, out, nullptr, nullptr, nullptr, nullptr, 768, 768);
    ln_kernel<<<ROWS, 256, 0, stream>>>(out, ln2_g, ln2_b, h2);
    gemm_bf16<128, 1><<<dim3(3072 / 128, 64), 256, 0, stream>>>(
        h2, fc1T, fc1_b, nullptr, nullptr, f1, nullptr, nullptr, nullptr, 3072, 768);
    gemm_bf16<64, 2><<<dim3(768 / 64, 64), 256, 0, stream>>>(
        f1, fc2T, fc2_b, out, out, nullptr, nullptr, nullptr, nullptr, 768, 3072);
}

// Round 5
// 346.569 us; speedup vs baseline: 5.6586x; 1.0182x over previous
//
#include <hip/hip_runtime.h>
#include <math.h>

#define DIM 768
#define HEADS 12
#define SEQ 2048
#define ROWS 4096
#define LN_EPS 1e-5f

typedef __attribute__((ext_vector_type(8))) short short8;
typedef __attribute__((ext_vector_type(4))) float floatx4;
typedef __attribute__((ext_vector_type(16))) float floatx16;
typedef unsigned short ushort_t;

__device__ __forceinline__ ushort_t f2bf(float x) {
    unsigned u = __float_as_uint(x);
    u += 0x7fff + ((u >> 16) & 1);
    return (ushort_t)(u >> 16);
}

__device__ __forceinline__ void gload_lds16(const void* g, void* l) {
    __builtin_amdgcn_global_load_lds((const __attribute__((address_space(1))) void*)g,
                                     (__attribute__((address_space(3))) void*)l, 16, 0, 0);
}

// ---------- fused weight convert+transpose for all four weight matrices ----------
__launch_bounds__(256)
__global__ void wconv_all(const float* __restrict__ w0, const float* __restrict__ w1,
                          const float* __restrict__ w2, const float* __restrict__ w3,
                          ushort_t* __restrict__ t0, ushort_t* __restrict__ t1,
                          ushort_t* __restrict__ t2, ushort_t* __restrict__ t3) {
    __shared__ __align__(16) ushort_t s[64][72];
    int bid = blockIdx.x;
    const float* W; ushort_t* WT; int K, N, nx, id;
    if (bid < 432)       { W = w0; WT = t0; K = 768;  N = 2304; nx = 36; id = bid; }
    else if (bid < 576)  { W = w1; WT = t1; K = 768;  N = 768;  nx = 12; id = bid - 432; }
    else if (bid < 1152) { W = w2; WT = t2; K = 768;  N = 3072; nx = 48; id = bid - 576; }
    else                 { W = w3; WT = t3; K = 3072; N = 768;  nx = 12; id = bid - 1152; }
    int tx = id % nx, ty = id / nx;
    int k0 = ty * 64, n0 = tx * 64;
    int t = threadIdx.x;
    int rr0 = t >> 4, c4 = (t & 15) * 4;
    for (int rr = rr0; rr < 64; rr += 16) {
        float4 w = *(const float4*)(W + (size_t)(k0 + rr) * N + n0 + c4);
        s[c4 + 0][rr] = f2bf(w.x); s[c4 + 1][rr] = f2bf(w.y);
        s[c4 + 2][rr] = f2bf(w.z); s[c4 + 3][rr] = f2bf(w.w);
    }
    __syncthreads();
    int nl = t >> 2, kq = (t & 3) * 16;
    uint4 a = *(const uint4*)&s[nl][kq];
    uint4 b = *(const uint4*)&s[nl][kq + 8];
    *(uint4*)(WT + (size_t)(n0 + nl) * K + k0 + kq) = a;
    *(uint4*)(WT + (size_t)(n0 + nl) * K + k0 + kq + 8) = b;
}

// ---------- elevation mask factors: G = exp(b*e), C2 = b*e ----------
__launch_bounds__(256)
__global__ void gelev_kernel(const float* __restrict__ elev, const float* __restrict__ barrier_p,
                             float* __restrict__ G, float* __restrict__ C2) {
    int i = blockIdx.x * 256 + threadIdx.x;
    float be = barrier_p[0] * elev[i];
    G[i]  = __expf(be);
    C2[i] = be;
}

// ---------- LayerNorm fp32 in -> bf16 out ----------
__launch_bounds__(256)
__global__ void ln_kernel(const float* __restrict__ x, const float* __restrict__ g,
                          const float* __restrict__ b, ushort_t* __restrict__ out) {
    int row = blockIdx.x;
    const float* xr = x + (size_t)row * DIM;
    int t = threadIdx.x;
    float v0 = xr[t], v1 = xr[t + 256], v2 = xr[t + 512];
    float s  = v0 + v1 + v2;
    float ss = v0 * v0 + v1 * v1 + v2 * v2;
    #pragma unroll
    for (int o = 32; o >= 1; o >>= 1) { s += __shfl_xor(s, o); ss += __shfl_xor(ss, o); }
    __shared__ float rs[4], rss[4];
    int wid = t >> 6, lane = t & 63;
    if (lane == 0) { rs[wid] = s; rss[wid] = ss; }
    __syncthreads();
    if (t == 0) {
        float S = 0.f, SS = 0.f;
        for (int i = 0; i < 4; i++) { S += rs[i]; SS += rss[i]; }
        rs[0] = S; rss[0] = SS;
    }
    __syncthreads();
    float mean = rs[0] * (1.0f / DIM);
    float var  = rss[0] * (1.0f / DIM) - mean * mean;
    float rstd = rsqrtf(var + LN_EPS);
    ushort_t* orow = out + (size_t)row * DIM;
    orow[t]       = f2bf((v0 - mean) * rstd * g[t]       + b[t]);
    orow[t + 256] = f2bf((v1 - mean) * rstd * g[t + 256] + b[t + 256]);
    orow[t + 512] = f2bf((v2 - mean) * rstd * g[t + 512] + b[t + 512]);
}

// ---------- 128x128 bf16 GEMM with 32x32x16 MFMA ----------
// EPI 0: qkv scatter (q*0.125 row-major, k row-major, v transposed)
// EPI 1: gelu -> bf16 row-major
template<int EPI>
__launch_bounds__(256)
__global__ void gemm32(const ushort_t* __restrict__ A, const ushort_t* __restrict__ WT,
                       const float* __restrict__ bias, ushort_t* __restrict__ outB,
                       ushort_t* __restrict__ qb, ushort_t* __restrict__ kb,
                       ushort_t* __restrict__ vb, int N, int K) {
    __shared__ __align__(16) ushort_t sA[128 * 32];
    __shared__ __align__(16) ushort_t sB[128 * 32];
    int t = threadIdx.x;
    int row0 = blockIdx.y * 128, col0 = blockIdx.x * 128;
    int wid = t >> 6, lane = t & 63, l31 = lane & 31, hb = lane >> 5;
    int wm = wid >> 1, wn = wid & 1;

    floatx16 acc[2][2];
    #pragma unroll
    for (int i = 0; i < 2; i++)
        #pragma unroll
        for (int j = 0; j < 2; j++)
            #pragma unroll
            for (int e = 0; e < 16; e++) acc[i][j][e] = 0.f;

    for (int k0 = 0; k0 < K; k0 += 32) {
        #pragma unroll
        for (int i = 0; i < 2; i++) {   // A+B tiles 128x32, swizzled source
            int c = i * 256 + t;
            int r = c >> 2, blk = c & 3;
            gload_lds16(A  + (size_t)(row0 + r) * K + k0 + ((blk ^ (r & 3)) << 3), &sA[c * 8]);
            gload_lds16(WT + (size_t)(col0 + r) * K + k0 + ((blk ^ (r & 3)) << 3), &sB[c * 8]);
        }
        __syncthreads();
        #pragma unroll
        for (int s = 0; s < 2; s++) {
            int blk = s * 2 + hb;
            int ra0 = wm * 64 + l31, ra1 = ra0 + 32;
            int rb0 = wn * 64 + l31, rb1 = rb0 + 32;
            short8 a0 = *(const short8*)&sA[ra0 * 32 + ((blk ^ (ra0 & 3)) << 3)];
            short8 a1 = *(const short8*)&sA[ra1 * 32 + ((blk ^ (ra1 & 3)) << 3)];
            short8 b0 = *(const short8*)&sB[rb0 * 32 + ((blk ^ (rb0 & 3)) << 3)];
            short8 b1 = *(const short8*)&sB[rb1 * 32 + ((blk ^ (rb1 & 3)) << 3)];
            acc[0][0] = __builtin_amdgcn_mfma_f32_32x32x16_bf16(a0, b0, acc[0][0], 0, 0, 0);
            acc[0][1] = __builtin_amdgcn_mfma_f32_32x32x16_bf16(a0, b1, acc[0][1], 0, 0, 0);
            acc[1][0] = __builtin_amdgcn_mfma_f32_32x32x16_bf16(a1, b0, acc[1][0], 0, 0, 0);
            acc[1][1] = __builtin_amdgcn_mfma_f32_32x32x16_bf16(a1, b1, acc[1][1], 0, 0, 0);
        }
        __syncthreads();
    }

    #pragma unroll
    for (int mt = 0; mt < 2; mt++) {
        #pragma unroll
        for (int nt = 0; nt < 2; nt++) {
            int gcol = col0 + wn * 64 + nt * 32 + l31;
            float bv = bias[gcol];
            if (EPI == 0) {
                int which = gcol / 768;
                int hc = gcol - which * 768;
                int hh = hc >> 6, d = hc & 63;
                #pragma unroll
                for (int rg = 0; rg < 16; rg++) {
                    int grow = row0 + wm * 64 + mt * 32 + (rg & 3) + 8 * (rg >> 2) + 4 * hb;
                    float v = acc[mt][nt][rg] + bv;
                    int b_ = grow >> 11, n = grow & 2047;
                    size_t bhh = (size_t)(b_ * 12 + hh);
                    if (which == 0)      qb[(bhh * 2048 + n) * 64 + d] = f2bf(v * 0.125f);
                    else if (which == 1) kb[(bhh * 2048 + n) * 64 + d] = f2bf(v);
                    else                 vb[(bhh * 64 + d) * 2048 + n] = f2bf(v);
                }
            } else {
                #pragma unroll
                for (int rg = 0; rg < 16; rg++) {
                    int grow = row0 + wm * 64 + mt * 32 + (rg & 3) + 8 * (rg >> 2) + 4 * hb;
                    float v = acc[mt][nt][rg] + bv;
                    v = 0.5f * v * (1.f + erff(v * 0.70710678118654752f));
                    outB[(size_t)grow * N + gcol] = f2bf(v);
                }
            }
        }
    }
}

// ---------- old 16x16 GEMM (kept for narrow proj/FC2): C = A@WT^T + bias + res ----------
template<int BN, int EPI>
__launch_bounds__(256)
__global__ void gemm_bf16(const ushort_t* __restrict__ A, const ushort_t* __restrict__ WT,
                          const float* __restrict__ bias, const float* __restrict__ res,
                          float* __restrict__ outF, int N, int K) {
    constexpr int NT = BN / 32;
    __shared__ __align__(16) ushort_t sA[64 * 32];
    __shared__ __align__(16) ushort_t sB[BN * 32];
    int t = threadIdx.x;
    int row0 = blockIdx.y * 64, col0 = blockIdx.x * BN;
    int wid = t >> 6, lane = t & 63;
    int wm = wid >> 1, wn = wid & 1;
    int cl = lane & 15, quad = lane >> 4;

    floatx4 acc[2][NT];
    #pragma unroll
    for (int i = 0; i < 2; i++)
        #pragma unroll
        for (int j = 0; j < NT; j++) { floatx4 z = {0.f, 0.f, 0.f, 0.f}; acc[i][j] = z; }

    for (int k0 = 0; k0 < K; k0 += 32) {
        {
            int r = t >> 2, sub = t & 3;
            gload_lds16(A + (size_t)(row0 + r) * K + k0 + sub * 8, &sA[t * 8]);
        }
        #pragma unroll
        for (int i = 0; i < BN / 64; i++) {
            int c = i * 256 + t;
            int r = c >> 2, sub = c & 3;
            gload_lds16(WT + (size_t)(col0 + r) * K + k0 + sub * 8, &sB[c * 8]);
        }
        __syncthreads();
        short8 a[2], b[NT];
        #pragma unroll
        for (int i = 0; i < 2; i++)
            a[i] = *(const short8*)&sA[(wm * 32 + i * 16 + cl) * 32 + quad * 8];
        #pragma unroll
        for (int j = 0; j < NT; j++)
            b[j] = *(const short8*)&sB[(wn * (BN / 2) + j * 16 + cl) * 32 + quad * 8];
        #pragma unroll
        for (int i = 0; i < 2; i++)
            #pragma unroll
            for (int j = 0; j < NT; j++)
                acc[i][j] = __builtin_amdgcn_mfma_f32_16x16x32_bf16(a[i], b[j], acc[i][j], 0, 0, 0);
        __syncthreads();
    }

    #pragma unroll
    for (int i = 0; i < 2; i++) {
        #pragma unroll
        for (int j = 0; j < NT; j++) {
            int gcol = col0 + wn * (BN / 2) + j * 16 + cl;
            float bv = bias[gcol];
            #pragma unroll
            for (int rg = 0; rg < 4; rg++) {
                int grow = row0 + wm * 32 + i * 16 + quad * 4 + rg;
                float v = acc[i][j][rg] + bv + res[(size_t)grow * N + gcol];
                outF[(size_t)grow * N + gcol] = v;
            }
        }
    }
}

// ---------- MFMA flash attention, 32x32x16, wave-local P, dbuf K/V ----------
// t = exp(q.k/8 + b*ei); p = t/(Gi+Gj) = exp(s)*sigmoid(b*(ei-ej))  [reference mask]
// out = sum(p*v)/sum(p)   (1e-8*sum_e term <= 2.1e-7 relative: dropped)
__launch_bounds__(256)
__global__ void attn_mfma(const ushort_t* __restrict__ qb, const ushort_t* __restrict__ kb,
                          const ushort_t* __restrict__ vb, const float* __restrict__ G,
                          const float* __restrict__ C2, ushort_t* __restrict__ attn) {
    __shared__ __align__(16) ushort_t Qs[4096];
    __shared__ __align__(16) ushort_t Ks[2][4096];
    __shared__ __align__(16) ushort_t Vt[2][4096];
    __shared__ __align__(16) ushort_t Ps[4096];
    __shared__ float semL[2][64];
    int qt = blockIdx.x, hh = blockIdx.y, b = blockIdx.z;
    int t = threadIdx.x, wid = t >> 6, lane = t & 63, l31 = lane & 31, hb = lane >> 5;
    int wm = wid >> 1, wn = wid & 1;
    int q0 = qt * 64;
    size_t bh = (size_t)(b * 12 + hh);

    const ushort_t* qbase = qb + (bh * 2048 + q0) * 64;
    #pragma unroll
    for (int i = 0; i < 2; i++) {
        int c = i * 256 + t, row = c >> 3, blk = c & 7;
        gload_lds16(qbase + (row << 6) + ((blk ^ (row & 7)) << 3), &Qs[c * 8]);
    }

    float gi[16]; floatx16 c2v;
    #pragma unroll
    for (int rg = 0; rg < 16; rg++) {
        int rr = (rg & 3) + 8 * (rg >> 2) + 4 * hb;
        int gr = b * 2048 + q0 + wm * 32 + rr;
        gi[rg] = G[gr]; c2v[rg] = C2[gr];
    }

    {   // prefetch tile 0
        const ushort_t* kbase = kb + bh * 2048 * 64;
        const ushort_t* vbase = vb + bh * 131072;
        #pragma unroll
        for (int i = 0; i < 2; i++) {
            int c = i * 256 + t, row = c >> 3, blk = c & 7;
            gload_lds16(kbase + (row << 6) + ((blk ^ (row & 7)) << 3), &Ks[0][c * 8]);
            gload_lds16(vbase + (size_t)row * 2048 + ((blk ^ (row & 7)) << 3), &Vt[0][c * 8]);
        }
    }

    floatx16 o0, o1;
    float semP[16];
    #pragma unroll
    for (int e = 0; e < 16; e++) { o0[e] = 0.f; o1[e] = 0.f; semP[e] = 0.f; }

    int arow = wm * 32 + l31, brow = wn * 32 + l31, x7 = l31 & 7;

    for (int kt = 0; kt < 32; kt++) {
        int cur = kt & 1;
        __syncthreads();
        if (kt < 31) {
            int k0n = (kt + 1) * 64;
            const ushort_t* kbase = kb + (bh * 2048 + k0n) * 64;
            const ushort_t* vbase = vb + bh * 131072 + k0n;
            #pragma unroll
            for (int i = 0; i < 2; i++) {
                int c = i * 256 + t, row = c >> 3, blk = c & 7;
                gload_lds16(kbase + (row << 6) + ((blk ^ (row & 7)) << 3), &Ks[cur ^ 1][c * 8]);
                gload_lds16(vbase + (size_t)row * 2048 + ((blk ^ (row & 7)) << 3), &Vt[cur ^ 1][c * 8]);
            }
        }
        float gj = G[b * 2048 + kt * 64 + wn * 32 + l31];

        floatx16 s = c2v;
        #pragma unroll
        for (int s4 = 0; s4 < 4; s4++) {
            short8 aq = *(const short8*)&Qs[(arow << 6) + (((s4 * 2 + hb) ^ x7) << 3)];
            short8 bk = *(const short8*)&Ks[cur][(brow << 6) + (((s4 * 2 + hb) ^ x7) << 3)];
            s = __builtin_amdgcn_mfma_f32_32x32x16_bf16(aq, bk, s, 0, 0, 0);
        }

        #pragma unroll
        for (int rg = 0; rg < 16; rg++) {
            int rr = (rg & 3) + 8 * (rg >> 2) + 4 * hb;
            int qrow = wm * 32 + rr;
            float tf = __expf(s[rg]);
            float p  = tf * __builtin_amdgcn_rcpf(gi[rg] + gj);
            semP[rg] += p;
            Ps[(qrow << 6) + (((wn * 4 + (l31 >> 3)) ^ (qrow & 7)) << 3) + (l31 & 7)] =
                (ushort_t)(__float_as_uint(p) >> 16);
        }

        #pragma unroll
        for (int s2 = 0; s2 < 2; s2++) {
            int blk = wn * 4 + s2 * 2 + hb;
            short8 ap  = *(const short8*)&Ps[(arow << 6) + ((blk ^ x7) << 3)];
            short8 bv0 = *(const short8*)&Vt[cur][(l31 << 6) + ((blk ^ x7) << 3)];
            short8 bv1 = *(const short8*)&Vt[cur][((32 + l31) << 6) + ((blk ^ x7) << 3)];
            o0 = __builtin_amdgcn_mfma_f32_32x32x16_bf16(ap, bv0, o0, 0, 0, 0);
            o1 = __builtin_amdgcn_mfma_f32_32x32x16_bf16(ap, bv1, o1, 0, 0, 0);
        }
    }

    // sem: butterfly over 32 j-lanes, then per-row write
    #pragma unroll
    for (int rg = 0; rg < 16; rg++) {
        float v = semP[rg];
        v += __shfl_xor(v, 1);  v += __shfl_xor(v, 2);  v += __shfl_xor(v, 4);
        v += __shfl_xor(v, 8);  v += __shfl_xor(v, 16);
        semP[rg] = v;
    }
    #pragma unroll
    for (int rg = 0; rg < 16; rg++) {
        int rr = (rg & 3) + 8 * (rg >> 2) + 4 * hb;
        if (l31 == rr) semL[wn][wm * 32 + rr] = semP[rg];
    }
    __syncthreads();                     // B1: loop done; Ks region now dead
    float* oL = (float*)Ks;
    if (wn == 0) {
        #pragma unroll
        for (int rg = 0; rg < 16; rg++) {
            int rr = (rg & 3) + 8 * (rg >> 2) + 4 * hb;
            oL[wm * 2048 + (rr << 6) + l31]      = o0[rg];
            oL[wm * 2048 + (rr << 6) + 32 + l31] = o1[rg];
        }
    }
    __syncthreads();                     // B2
    if (wn == 1) {
        #pragma unroll
        for (int rg = 0; rg < 16; rg++) {
            int rr = (rg & 3) + 8 * (rg >> 2) + 4 * hb;
            int qrow = wm * 32 + rr;
            float inv = __builtin_amdgcn_rcpf(semL[0][qrow] + semL[1][qrow]);
            float v0 = o0[rg] + oL[wm * 2048 + (rr << 6) + l31];
            float v1 = o1[rg] + oL[wm * 2048 + (rr << 6) + 32 + l31];
            Ps[(qrow << 6) + ((((l31 >> 3)) ^ (qrow & 7)) << 3) + (l31 & 7)]     = f2bf(v0 * inv);
            Ps[(qrow << 6) + (((4 + (l31 >> 3)) ^ (qrow & 7)) << 3) + (l31 & 7)] = f2bf(v1 * inv);
        }
    }
    __syncthreads();                     // B3
    int row = t >> 2, ch = t & 3;
    uint4 u0 = *(const uint4*)&Ps[(row << 6) + (((ch * 2    ) ^ (row & 7)) << 3)];
    uint4 u1 = *(const uint4*)&Ps[(row << 6) + (((ch * 2 + 1) ^ (row & 7)) << 3)];
    size_t oa = (size_t)(b * 2048 + q0 + row) * 768 + hh * 64 + ch * 16;
    *(uint4*)(attn + oa)     = u0;
    *(uint4*)(attn + oa + 8) = u1;
}

extern "C" void kernel_launch(void* const* d_in, const int* in_sizes, int n_in,
                              void* d_out, int out_size, void* d_ws, size_t ws_size,
                              hipStream_t stream) {
    const float* x      = (const float*)d_in[0];
    const float* elev   = (const float*)d_in[1];
    const float* qkv_w  = (const float*)d_in[2];
    const float* qkv_b  = (const float*)d_in[3];
    const float* proj_w = (const float*)d_in[4];
    const float* proj_b = (const float*)d_in[5];
    const float* ln1_g  = (const float*)d_in[6];
    const float* ln1_b  = (const float*)d_in[7];
    const float* ln2_g  = (const float*)d_in[8];
    const float* ln2_b  = (const float*)d_in[9];
    const float* fc1_w  = (const float*)d_in[10];
    const float* fc1_b  = (const float*)d_in[11];
    const float* fc2_w  = (const float*)d_in[12];
    const float* fc2_b  = (const float*)d_in[13];
    const float* barrier= (const float*)d_in[14];
    float* out = (float*)d_out;
    char* ws = (char*)d_ws;

    ushort_t* h    = (ushort_t*)(ws + 0);         // 6291456 B
    ushort_t* qb   = (ushort_t*)(ws + 6291456);   // 6291456
    ushort_t* kb   = (ushort_t*)(ws + 12582912);  // 6291456
    ushort_t* vb   = (ushort_t*)(ws + 18874368);  // 6291456
    ushort_t* f1   = (ushort_t*)(ws + 0);         // 25165824 (overlays h,qb,kb,vb)
    ushort_t* attn = (ushort_t*)(ws + 25165824);  // 6291456
    ushort_t* h2   = (ushort_t*)(ws + 31457280);  // 6291456
    float*    Gf   = (float*)(ws + 31457280);     // overlays h2 region, dead before ln2
    float*    C2f  = (float*)(ws + 31473664);
    ushort_t* qkvT = (ushort_t*)(ws + 37748736);  // 3538944
    ushort_t* projT= (ushort_t*)(ws + 41287680);  // 1179648
    ushort_t* fc1T = (ushort_t*)(ws + 42467328);  // 4718592
    ushort_t* fc2T = (ushort_t*)(ws + 47185920);  // 4718592

    wconv_all<<<1728, 256, 0, stream>>>(qkv_w, proj_w, fc1_w, fc2_w, qkvT, projT, fc1T, fc2T);
    gelev_kernel<<<16, 256, 0, stream>>>(elev, barrier, Gf, C2f);

    ln_kernel<<<ROWS, 256, 0, stream>>>(x, ln1_g, ln1_b, h);
    gemm32<0><<<dim3(2304 / 128, 32), 256, 0, stream>>>(
        h, qkvT, qkv_b, nullptr, qb, kb, vb, 2304, 768);
    attn_mfma<<<dim3(32, HEADS, 2), 256, 0, stream>>>(qb, kb, vb, Gf, C2f, attn);
    gemm_bf16<64, 2><<<dim3(768 / 64, 64), 256, 0, stream>>>(
        attn, projT, proj_b, x, out, 768, 768);
    ln_kernel<<<ROWS, 256, 0, stream>>>(out, ln2_g, ln2_b, h2);
    gemm32<1><<<dim3(3072 / 128, 32), 256, 0, stream>>>(
        h2, fc1T, fc1_b, f1, nullptr, nullptr, nullptr, 3072, 768);
    gemm_bf16<64, 2><<<dim3(768 / 64, 64), 256, 0, stream>>>(
        f1, fc2T, fc2_b, out, out, 768, 3072);
}

// Round 6
// 324.446 us; speedup vs baseline: 6.0444x; 1.0682x over previous
//
#include <hip/hip_runtime.h>
#include <math.h>

#define DIM 768
#define HEADS 12
#define SEQ 2048
#define ROWS 4096
#define LN_EPS 1e-5f

typedef __attribute__((ext_vector_type(8))) short short8;
typedef __attribute__((ext_vector_type(4))) float floatx4;
typedef __attribute__((ext_vector_type(16))) float floatx16;
typedef unsigned short ushort_t;

__device__ __forceinline__ ushort_t f2bf(float x) {
    unsigned u = __float_as_uint(x);
    u += 0x7fff + ((u >> 16) & 1);
    return (ushort_t)(u >> 16);
}

__device__ __forceinline__ void gload_lds16(const void* g, void* l) {
    __builtin_amdgcn_global_load_lds((const __attribute__((address_space(1))) void*)g,
                                     (__attribute__((address_space(3))) void*)l, 16, 0, 0);
}

// ---------- fused weight convert+transpose for all four weight matrices ----------
__launch_bounds__(256)
__global__ void wconv_all(const float* __restrict__ w0, const float* __restrict__ w1,
                          const float* __restrict__ w2, const float* __restrict__ w3,
                          ushort_t* __restrict__ t0, ushort_t* __restrict__ t1,
                          ushort_t* __restrict__ t2, ushort_t* __restrict__ t3) {
    __shared__ __align__(16) ushort_t s[64][72];
    int bid = blockIdx.x;
    const float* W; ushort_t* WT; int K, N, nx, id;
    if (bid < 432)       { W = w0; WT = t0; K = 768;  N = 2304; nx = 36; id = bid; }
    else if (bid < 576)  { W = w1; WT = t1; K = 768;  N = 768;  nx = 12; id = bid - 432; }
    else if (bid < 1152) { W = w2; WT = t2; K = 768;  N = 3072; nx = 48; id = bid - 576; }
    else                 { W = w3; WT = t3; K = 3072; N = 768;  nx = 12; id = bid - 1152; }
    int tx = id % nx, ty = id / nx;
    int k0 = ty * 64, n0 = tx * 64;
    int t = threadIdx.x;
    int rr0 = t >> 4, c4 = (t & 15) * 4;
    for (int rr = rr0; rr < 64; rr += 16) {
        float4 w = *(const float4*)(W + (size_t)(k0 + rr) * N + n0 + c4);
        s[c4 + 0][rr] = f2bf(w.x); s[c4 + 1][rr] = f2bf(w.y);
        s[c4 + 2][rr] = f2bf(w.z); s[c4 + 3][rr] = f2bf(w.w);
    }
    __syncthreads();
    int nl = t >> 2, kq = (t & 3) * 16;
    uint4 a = *(const uint4*)&s[nl][kq];
    uint4 b = *(const uint4*)&s[nl][kq + 8];
    *(uint4*)(WT + (size_t)(n0 + nl) * K + k0 + kq) = a;
    *(uint4*)(WT + (size_t)(n0 + nl) * K + k0 + kq + 8) = b;
}

// ---------- elevation mask factors: G = exp(b*e), C2 = b*e ----------
__launch_bounds__(256)
__global__ void gelev_kernel(const float* __restrict__ elev, const float* __restrict__ barrier_p,
                             float* __restrict__ G, float* __restrict__ C2) {
    int i = blockIdx.x * 256 + threadIdx.x;
    float be = barrier_p[0] * elev[i];
    G[i]  = __expf(be);
    C2[i] = be;
}

// ---------- LayerNorm fp32 in -> bf16 out ----------
__launch_bounds__(256)
__global__ void ln_kernel(const float* __restrict__ x, const float* __restrict__ g,
                          const float* __restrict__ b, ushort_t* __restrict__ out) {
    int row = blockIdx.x;
    const float* xr = x + (size_t)row * DIM;
    int t = threadIdx.x;
    float v0 = xr[t], v1 = xr[t + 256], v2 = xr[t + 512];
    float s  = v0 + v1 + v2;
    float ss = v0 * v0 + v1 * v1 + v2 * v2;
    #pragma unroll
    for (int o = 32; o >= 1; o >>= 1) { s += __shfl_xor(s, o); ss += __shfl_xor(ss, o); }
    __shared__ float rs[4], rss[4];
    int wid = t >> 6, lane = t & 63;
    if (lane == 0) { rs[wid] = s; rss[wid] = ss; }
    __syncthreads();
    if (t == 0) {
        float S = 0.f, SS = 0.f;
        for (int i = 0; i < 4; i++) { S += rs[i]; SS += rss[i]; }
        rs[0] = S; rss[0] = SS;
    }
    __syncthreads();
    float mean = rs[0] * (1.0f / DIM);
    float var  = rss[0] * (1.0f / DIM) - mean * mean;
    float rstd = rsqrtf(var + LN_EPS);
    ushort_t* orow = out + (size_t)row * DIM;
    orow[t]       = f2bf((v0 - mean) * rstd * g[t]       + b[t]);
    orow[t + 256] = f2bf((v1 - mean) * rstd * g[t + 256] + b[t + 256]);
    orow[t + 512] = f2bf((v2 - mean) * rstd * g[t + 512] + b[t + 512]);
}

// ---------- 128x128 bf16 GEMM with 32x32x16 MFMA ----------
// EPI 0: qkv scatter (q*0.125 row-major, k row-major, v transposed)
// EPI 1: gelu -> bf16 row-major
template<int EPI>
__launch_bounds__(256)
__global__ void gemm32(const ushort_t* __restrict__ A, const ushort_t* __restrict__ WT,
                       const float* __restrict__ bias, ushort_t* __restrict__ outB,
                       ushort_t* __restrict__ qb, ushort_t* __restrict__ kb,
                       ushort_t* __restrict__ vb, int N, int K) {
    __shared__ __align__(16) ushort_t sA[128 * 32];
    __shared__ __align__(16) ushort_t sB[128 * 32];
    int t = threadIdx.x;
    int row0 = blockIdx.y * 128, col0 = blockIdx.x * 128;
    int wid = t >> 6, lane = t & 63, l31 = lane & 31, hb = lane >> 5;
    int wm = wid >> 1, wn = wid & 1;

    floatx16 acc[2][2];
    #pragma unroll
    for (int i = 0; i < 2; i++)
        #pragma unroll
        for (int j = 0; j < 2; j++)
            #pragma unroll
            for (int e = 0; e < 16; e++) acc[i][j][e] = 0.f;

    for (int k0 = 0; k0 < K; k0 += 32) {
        #pragma unroll
        for (int i = 0; i < 2; i++) {
            int c = i * 256 + t;
            int r = c >> 2, blk = c & 3;
            gload_lds16(A  + (size_t)(row0 + r) * K + k0 + ((blk ^ (r & 3)) << 3), &sA[c * 8]);
            gload_lds16(WT + (size_t)(col0 + r) * K + k0 + ((blk ^ (r & 3)) << 3), &sB[c * 8]);
        }
        __syncthreads();
        #pragma unroll
        for (int s = 0; s < 2; s++) {
            int blk = s * 2 + hb;
            int ra0 = wm * 64 + l31, ra1 = ra0 + 32;
            int rb0 = wn * 64 + l31, rb1 = rb0 + 32;
            short8 a0 = *(const short8*)&sA[ra0 * 32 + ((blk ^ (ra0 & 3)) << 3)];
            short8 a1 = *(const short8*)&sA[ra1 * 32 + ((blk ^ (ra1 & 3)) << 3)];
            short8 b0 = *(const short8*)&sB[rb0 * 32 + ((blk ^ (rb0 & 3)) << 3)];
            short8 b1 = *(const short8*)&sB[rb1 * 32 + ((blk ^ (rb1 & 3)) << 3)];
            acc[0][0] = __builtin_amdgcn_mfma_f32_32x32x16_bf16(a0, b0, acc[0][0], 0, 0, 0);
            acc[0][1] = __builtin_amdgcn_mfma_f32_32x32x16_bf16(a0, b1, acc[0][1], 0, 0, 0);
            acc[1][0] = __builtin_amdgcn_mfma_f32_32x32x16_bf16(a1, b0, acc[1][0], 0, 0, 0);
            acc[1][1] = __builtin_amdgcn_mfma_f32_32x32x16_bf16(a1, b1, acc[1][1], 0, 0, 0);
        }
        __syncthreads();
    }

    #pragma unroll
    for (int mt = 0; mt < 2; mt++) {
        #pragma unroll
        for (int nt = 0; nt < 2; nt++) {
            int gcol = col0 + wn * 64 + nt * 32 + l31;
            float bv = bias[gcol];
            if (EPI == 0) {
                int which = gcol / 768;
                int hc = gcol - which * 768;
                int hh = hc >> 6, d = hc & 63;
                #pragma unroll
                for (int rg = 0; rg < 16; rg++) {
                    int grow = row0 + wm * 64 + mt * 32 + (rg & 3) + 8 * (rg >> 2) + 4 * hb;
                    float v = acc[mt][nt][rg] + bv;
                    int b_ = grow >> 11, n = grow & 2047;
                    size_t bhh = (size_t)(b_ * 12 + hh);
                    if (which == 0)      qb[(bhh * 2048 + n) * 64 + d] = f2bf(v * 0.125f);
                    else if (which == 1) kb[(bhh * 2048 + n) * 64 + d] = f2bf(v);
                    else                 vb[(bhh * 64 + d) * 2048 + n] = f2bf(v);
                }
            } else {
                #pragma unroll
                for (int rg = 0; rg < 16; rg++) {
                    int grow = row0 + wm * 64 + mt * 32 + (rg & 3) + 8 * (rg >> 2) + 4 * hb;
                    float v = acc[mt][nt][rg] + bv;
                    v = 0.5f * v * (1.f + erff(v * 0.70710678118654752f));
                    outB[(size_t)grow * N + gcol] = f2bf(v);
                }
            }
        }
    }
}

// ---------- 16x16 GEMM (narrow proj/FC2): C = A@WT^T + bias + res -> fp32 ----------
template<int BN, int EPI>
__launch_bounds__(256)
__global__ void gemm_bf16(const ushort_t* __restrict__ A, const ushort_t* __restrict__ WT,
                          const float* __restrict__ bias, const float* __restrict__ res,
                          float* __restrict__ outF, int N, int K) {
    constexpr int NT = BN / 32;
    __shared__ __align__(16) ushort_t sA[64 * 32];
    __shared__ __align__(16) ushort_t sB[BN * 32];
    int t = threadIdx.x;
    int row0 = blockIdx.y * 64, col0 = blockIdx.x * BN;
    int wid = t >> 6, lane = t & 63;
    int wm = wid >> 1, wn = wid & 1;
    int cl = lane & 15, quad = lane >> 4;

    floatx4 acc[2][NT];
    #pragma unroll
    for (int i = 0; i < 2; i++)
        #pragma unroll
        for (int j = 0; j < NT; j++) { floatx4 z = {0.f, 0.f, 0.f, 0.f}; acc[i][j] = z; }

    for (int k0 = 0; k0 < K; k0 += 32) {
        {
            int r = t >> 2, sub = t & 3;
            gload_lds16(A + (size_t)(row0 + r) * K + k0 + sub * 8, &sA[t * 8]);
        }
        #pragma unroll
        for (int i = 0; i < BN / 64; i++) {
            int c = i * 256 + t;
            int r = c >> 2, sub = c & 3;
            gload_lds16(WT + (size_t)(col0 + r) * K + k0 + sub * 8, &sB[c * 8]);
        }
        __syncthreads();
        short8 a[2], b[NT];
        #pragma unroll
        for (int i = 0; i < 2; i++)
            a[i] = *(const short8*)&sA[(wm * 32 + i * 16 + cl) * 32 + quad * 8];
        #pragma unroll
        for (int j = 0; j < NT; j++)
            b[j] = *(const short8*)&sB[(wn * (BN / 2) + j * 16 + cl) * 32 + quad * 8];
        #pragma unroll
        for (int i = 0; i < 2; i++)
            #pragma unroll
            for (int j = 0; j < NT; j++)
                acc[i][j] = __builtin_amdgcn_mfma_f32_16x16x32_bf16(a[i], b[j], acc[i][j], 0, 0, 0);
        __syncthreads();
    }

    #pragma unroll
    for (int i = 0; i < 2; i++) {
        #pragma unroll
        for (int j = 0; j < NT; j++) {
            int gcol = col0 + wn * (BN / 2) + j * 16 + cl;
            float bv = bias[gcol];
            #pragma unroll
            for (int rg = 0; rg < 4; rg++) {
                int grow = row0 + wm * 32 + i * 16 + quad * 4 + rg;
                float v = acc[i][j][rg] + bv + res[(size_t)grow * N + gcol];
                outF[(size_t)grow * N + gcol] = v;
            }
        }
    }
}

// ---------- MFMA flash attention, 16x16x32, STATIC double-buffers ----------
// Separate __shared__ objects + unroll-2 so alias analysis lets the prefetch
// stay in flight across the tile's ds_reads (no conservative vmcnt(0)).
// t = exp(q.k/8 + b*ei); p = t/(Gi+Gj) = exp(s)*sigmoid(b*(ei-ej)); out = sum(p*v)/sum(p)

#define PREFETCH(K0N, KSN, VTN)                                                   \
    {                                                                             \
        const ushort_t* kbase_ = kb + (bh * 2048 + (K0N)) * 64;                   \
        const ushort_t* vbase_ = vb + bh * 131072 + (K0N);                        \
        int c0_ = t, r0_ = c0_ >> 3, b0_ = c0_ & 7;                               \
        gload_lds16(kbase_ + (r0_ << 6) + ((b0_ ^ (r0_ & 7)) << 3), &KSN[c0_ * 8]); \
        gload_lds16(vbase_ + (size_t)r0_ * 2048 + ((b0_ ^ (r0_ & 7)) << 3), &VTN[c0_ * 8]); \
        int c1_ = 256 + t, r1_ = c1_ >> 3, b1_ = c1_ & 7;                         \
        gload_lds16(kbase_ + (r1_ << 6) + ((b1_ ^ (r1_ & 7)) << 3), &KSN[c1_ * 8]); \
        gload_lds16(vbase_ + (size_t)r1_ * 2048 + ((b1_ ^ (r1_ & 7)) << 3), &VTN[c1_ * 8]); \
    }

#define ATTN_TILE(KT, KSC, VTC, KSN, VTN)                                         \
    {                                                                             \
        __syncthreads();                                                          \
        if ((KT) < 31) PREFETCH(((KT) + 1) * 64, KSN, VTN)                        \
        float gjv_[4];                                                            \
        gjv_[0] = G[b * 2048 + (KT) * 64 + cl];                                   \
        gjv_[1] = G[b * 2048 + (KT) * 64 + 16 + cl];                              \
        gjv_[2] = G[b * 2048 + (KT) * 64 + 32 + cl];                              \
        gjv_[3] = G[b * 2048 + (KT) * 64 + 48 + cl];                              \
        floatx4 s_[4];                                                            \
        s_[0] = c2init; s_[1] = c2init; s_[2] = c2init; s_[3] = c2init;           \
        _Pragma("unroll")                                                         \
        for (int kh = 0; kh < 2; kh++) {                                          \
            short8 aq_ = *(const short8*)&Qs[((wid * 16 + cl) << 6) + (((kh * 4 + quad) ^ (cl & 7)) << 3)]; \
            _Pragma("unroll")                                                     \
            for (int nt = 0; nt < 4; nt++) {                                      \
                short8 bk_ = *(const short8*)&KSC[((nt * 16 + cl) << 6) + (((kh * 4 + quad) ^ (cl & 7)) << 3)]; \
                s_[nt] = __builtin_amdgcn_mfma_f32_16x16x32_bf16(aq_, bk_, s_[nt], 0, 0, 0); \
            }                                                                     \
        }                                                                         \
        _Pragma("unroll")                                                         \
        for (int rg = 0; rg < 4; rg++) {                                          \
            int prow_ = wid * 16 + quad * 4 + rg;                                 \
            int r8_ = prow_ & 7, pb_ = prow_ << 6, cs_ = cl & 7, ch_ = cl >> 3;   \
            _Pragma("unroll")                                                     \
            for (int nt = 0; nt < 4; nt++) {                                      \
                float tf_ = __expf(s_[nt][rg]);                                   \
                float p_  = tf_ * __builtin_amdgcn_rcpf(gi[rg] + gjv_[nt]);       \
                sem[rg] += p_;                                                    \
                Ps[pb_ + (((nt * 2 + ch_) ^ r8_) << 3) + cs_] = (ushort_t)(__float_as_uint(p_) >> 16); \
            }                                                                     \
        }                                                                         \
        _Pragma("unroll")                                                         \
        for (int kh = 0; kh < 2; kh++) {                                          \
            short8 ap_ = *(const short8*)&Ps[((wid * 16 + cl) << 6) + (((kh * 4 + quad) ^ (cl & 7)) << 3)]; \
            _Pragma("unroll")                                                     \
            for (int dt = 0; dt < 4; dt++) {                                      \
                short8 bv_ = *(const short8*)&VTC[((dt * 16 + cl) << 6) + (((kh * 4 + quad) ^ (cl & 7)) << 3)]; \
                o[dt] = __builtin_amdgcn_mfma_f32_16x16x32_bf16(ap_, bv_, o[dt], 0, 0, 0); \
            }                                                                     \
        }                                                                         \
    }

__launch_bounds__(256)
__global__ void attn_mfma(const ushort_t* __restrict__ qb, const ushort_t* __restrict__ kb,
                          const ushort_t* __restrict__ vb, const float* __restrict__ G,
                          const float* __restrict__ C2, ushort_t* __restrict__ attn) {
    __shared__ __align__(16) ushort_t Qs[4096];
    __shared__ __align__(16) ushort_t Ks0[4096];
    __shared__ __align__(16) ushort_t Ks1[4096];
    __shared__ __align__(16) ushort_t Vt0[4096];
    __shared__ __align__(16) ushort_t Vt1[4096];
    __shared__ __align__(16) ushort_t Ps[4096];
    int qt = blockIdx.x, h = blockIdx.y, b = blockIdx.z;
    int t = threadIdx.x, wid = t >> 6, lane = t & 63;
    int cl = lane & 15, quad = lane >> 4;
    int q0 = qt * 64;
    size_t bh = (size_t)(b * 12 + h);

    // stage Q, XOR-swizzled via permuted glds SOURCE addresses
    const ushort_t* qbase = qb + (bh * 2048 + q0) * 64;
    #pragma unroll
    for (int i = 0; i < 2; i++) {
        int c = i * 256 + t, row = c >> 3, blk = c & 7;
        gload_lds16(qbase + (row << 6) + ((blk ^ (row & 7)) << 3), &Qs[c * 8]);
    }
    // per-row mask params (4 consecutive rows per thread)
    int qrow4 = b * 2048 + q0 + wid * 16 + quad * 4;
    float4 g4  = *(const float4*)(G  + qrow4);
    float4 c24 = *(const float4*)(C2 + qrow4);
    float gi[4]  = {g4.x, g4.y, g4.z, g4.w};
    floatx4 c2init = {c24.x, c24.y, c24.z, c24.w};

    // prefetch tile 0 into static buffer pair 0
    PREFETCH(0, Ks0, Vt0)

    floatx4 o[4];
    #pragma unroll
    for (int j = 0; j < 4; j++) { floatx4 z = {0.f, 0.f, 0.f, 0.f}; o[j] = z; }
    float sem[4] = {0.f, 0.f, 0.f, 0.f};

    for (int kt = 0; kt < 32; kt += 2) {
        ATTN_TILE(kt,     Ks0, Vt0, Ks1, Vt1)
        ATTN_TILE(kt + 1, Ks1, Vt1, Ks0, Vt0)
    }

    #pragma unroll
    for (int rg = 0; rg < 4; rg++) {
        float m = sem[rg];
        #pragma unroll
        for (int off = 1; off < 16; off <<= 1) m += __shfl_xor(m, off);
        float inv = __builtin_amdgcn_rcpf(m);
        int grow = b * 2048 + q0 + wid * 16 + quad * 4 + rg;
        #pragma unroll
        for (int dt = 0; dt < 4; dt++)
            attn[(size_t)grow * 768 + h * 64 + dt * 16 + cl] = f2bf(o[dt][rg] * inv);
    }
}

extern "C" void kernel_launch(void* const* d_in, const int* in_sizes, int n_in,
                              void* d_out, int out_size, void* d_ws, size_t ws_size,
                              hipStream_t stream) {
    const float* x      = (const float*)d_in[0];
    const float* elev   = (const float*)d_in[1];
    const float* qkv_w  = (const float*)d_in[2];
    const float* qkv_b  = (const float*)d_in[3];
    const float* proj_w = (const float*)d_in[4];
    const float* proj_b = (const float*)d_in[5];
    const float* ln1_g  = (const float*)d_in[6];
    const float* ln1_b  = (const float*)d_in[7];
    const float* ln2_g  = (const float*)d_in[8];
    const float* ln2_b  = (const float*)d_in[9];
    const float* fc1_w  = (const float*)d_in[10];
    const float* fc1_b  = (const float*)d_in[11];
    const float* fc2_w  = (const float*)d_in[12];
    const float* fc2_b  = (const float*)d_in[13];
    const float* barrier= (const float*)d_in[14];
    float* out = (float*)d_out;
    char* ws = (char*)d_ws;

    ushort_t* h    = (ushort_t*)(ws + 0);         // 6291456 B
    ushort_t* qb   = (ushort_t*)(ws + 6291456);   // 6291456
    ushort_t* kb   = (ushort_t*)(ws + 12582912);  // 6291456
    ushort_t* vb   = (ushort_t*)(ws + 18874368);  // 6291456
    ushort_t* f1   = (ushort_t*)(ws + 0);         // 25165824 (overlays h,qb,kb,vb)
    ushort_t* attn = (ushort_t*)(ws + 25165824);  // 6291456
    ushort_t* h2   = (ushort_t*)(ws + 31457280);  // 6291456
    float*    Gf   = (float*)(ws + 31457280);     // overlays h2 region, dead before ln2
    float*    C2f  = (float*)(ws + 31473664);
    ushort_t* qkvT = (ushort_t*)(ws + 37748736);  // 3538944
    ushort_t* projT= (ushort_t*)(ws + 41287680);  // 1179648
    ushort_t* fc1T = (ushort_t*)(ws + 42467328);  // 4718592
    ushort_t* fc2T = (ushort_t*)(ws + 47185920);  // 4718592

    wconv_all<<<1728, 256, 0, stream>>>(qkv_w, proj_w, fc1_w, fc2_w, qkvT, projT, fc1T, fc2T);
    gelev_kernel<<<16, 256, 0, stream>>>(elev, barrier, Gf, C2f);

    ln_kernel<<<ROWS, 256, 0, stream>>>(x, ln1_g, ln1_b, h);
    gemm32<0><<<dim3(2304 / 128, 32), 256, 0, stream>>>(
        h, qkvT, qkv_b, nullptr, qb, kb, vb, 2304, 768);
    attn_mfma<<<dim3(32, HEADS, 2), 256, 0, stream>>>(qb, kb, vb, Gf, C2f, attn);
    gemm_bf16<64, 2><<<dim3(768 / 64, 64), 256, 0, stream>>>(
        attn, projT, proj_b, x, out, 768, 768);
    ln_kernel<<<ROWS, 256, 0, stream>>>(out, ln2_g, ln2_b, h2);
    gemm32<1><<<dim3(3072 / 128, 32), 256, 0, stream>>>(
        h2, fc1T, fc1_b, f1, nullptr, nullptr, nullptr, 3072, 768);
    gemm_bf16<64, 2><<<dim3(768 / 64, 64), 256, 0, stream>>>(
        f1, fc2T, fc2_b, out, out, 768, 3072);
}

// Round 7
// 319.862 us; speedup vs baseline: 6.1310x; 1.0143x over previous
//
#include <hip/hip_runtime.h>
#include <math.h>

#define DIM 768
#define HEADS 12
#define SEQ 2048
#define ROWS 4096
#define LN_EPS 1e-5f

typedef __attribute__((ext_vector_type(8))) short short8;
typedef __attribute__((ext_vector_type(4))) float floatx4;
typedef __attribute__((ext_vector_type(16))) float floatx16;
typedef unsigned short ushort_t;

__device__ __forceinline__ ushort_t f2bf(float x) {
    unsigned u = __float_as_uint(x);
    u += 0x7fff + ((u >> 16) & 1);
    return (ushort_t)(u >> 16);
}

__device__ __forceinline__ void gload_lds16(const void* g, void* l) {
    __builtin_amdgcn_global_load_lds((const __attribute__((address_space(1))) void*)g,
                                     (__attribute__((address_space(3))) void*)l, 16, 0, 0);
}

// ---------- fused weight convert+transpose for all four weight matrices ----------
__launch_bounds__(256)
__global__ void wconv_all(const float* __restrict__ w0, const float* __restrict__ w1,
                          const float* __restrict__ w2, const float* __restrict__ w3,
                          ushort_t* __restrict__ t0, ushort_t* __restrict__ t1,
                          ushort_t* __restrict__ t2, ushort_t* __restrict__ t3) {
    __shared__ __align__(16) ushort_t s[64][72];
    int bid = blockIdx.x;
    const float* W; ushort_t* WT; int K, N, nx, id;
    if (bid < 432)       { W = w0; WT = t0; K = 768;  N = 2304; nx = 36; id = bid; }
    else if (bid < 576)  { W = w1; WT = t1; K = 768;  N = 768;  nx = 12; id = bid - 432; }
    else if (bid < 1152) { W = w2; WT = t2; K = 768;  N = 3072; nx = 48; id = bid - 576; }
    else                 { W = w3; WT = t3; K = 3072; N = 768;  nx = 12; id = bid - 1152; }
    int tx = id % nx, ty = id / nx;
    int k0 = ty * 64, n0 = tx * 64;
    int t = threadIdx.x;
    int rr0 = t >> 4, c4 = (t & 15) * 4;
    for (int rr = rr0; rr < 64; rr += 16) {
        float4 w = *(const float4*)(W + (size_t)(k0 + rr) * N + n0 + c4);
        s[c4 + 0][rr] = f2bf(w.x); s[c4 + 1][rr] = f2bf(w.y);
        s[c4 + 2][rr] = f2bf(w.z); s[c4 + 3][rr] = f2bf(w.w);
    }
    __syncthreads();
    int nl = t >> 2, kq = (t & 3) * 16;
    uint4 a = *(const uint4*)&s[nl][kq];
    uint4 b = *(const uint4*)&s[nl][kq + 8];
    *(uint4*)(WT + (size_t)(n0 + nl) * K + k0 + kq) = a;
    *(uint4*)(WT + (size_t)(n0 + nl) * K + k0 + kq + 8) = b;
}

// ---------- elevation mask factors: G = exp(b*e), C2 = b*e ----------
__launch_bounds__(256)
__global__ void gelev_kernel(const float* __restrict__ elev, const float* __restrict__ barrier_p,
                             float* __restrict__ G, float* __restrict__ C2) {
    int i = blockIdx.x * 256 + threadIdx.x;
    float be = barrier_p[0] * elev[i];
    G[i]  = __expf(be);
    C2[i] = be;
}

// ---------- LayerNorm fp32 in -> bf16 out ----------
__launch_bounds__(256)
__global__ void ln_kernel(const float* __restrict__ x, const float* __restrict__ g,
                          const float* __restrict__ b, ushort_t* __restrict__ out) {
    int row = blockIdx.x;
    const float* xr = x + (size_t)row * DIM;
    int t = threadIdx.x;
    float v0 = xr[t], v1 = xr[t + 256], v2 = xr[t + 512];
    float s  = v0 + v1 + v2;
    float ss = v0 * v0 + v1 * v1 + v2 * v2;
    #pragma unroll
    for (int o = 32; o >= 1; o >>= 1) { s += __shfl_xor(s, o); ss += __shfl_xor(ss, o); }
    __shared__ float rs[4], rss[4];
    int wid = t >> 6, lane = t & 63;
    if (lane == 0) { rs[wid] = s; rss[wid] = ss; }
    __syncthreads();
    if (t == 0) {
        float S = 0.f, SS = 0.f;
        for (int i = 0; i < 4; i++) { S += rs[i]; SS += rss[i]; }
        rs[0] = S; rss[0] = SS;
    }
    __syncthreads();
    float mean = rs[0] * (1.0f / DIM);
    float var  = rss[0] * (1.0f / DIM) - mean * mean;
    float rstd = rsqrtf(var + LN_EPS);
    ushort_t* orow = out + (size_t)row * DIM;
    orow[t]       = f2bf((v0 - mean) * rstd * g[t]       + b[t]);
    orow[t + 256] = f2bf((v1 - mean) * rstd * g[t + 256] + b[t + 256]);
    orow[t + 512] = f2bf((v2 - mean) * rstd * g[t + 512] + b[t + 512]);
}

// ---------- 128x128 bf16 GEMM, 32x32x16 MFMA, static double-buffered K-loop ----------
// EPI 0: qkv scatter (q*0.125 row-major, k row-major, v transposed)
// EPI 1: gelu -> bf16 row-major

#define G32_PREFETCH(K0, SA, SB)                                                      \
    {                                                                                 \
        int c0_ = t, r0_ = c0_ >> 2, bl0_ = c0_ & 3;                                  \
        gload_lds16(A  + (size_t)(row0 + r0_) * K + (K0) + ((bl0_ ^ (r0_ & 3)) << 3), &SA[c0_ * 8]); \
        gload_lds16(WT + (size_t)(col0 + r0_) * K + (K0) + ((bl0_ ^ (r0_ & 3)) << 3), &SB[c0_ * 8]); \
        int c1_ = 256 + t, r1_ = c1_ >> 2, bl1_ = c1_ & 3;                            \
        gload_lds16(A  + (size_t)(row0 + r1_) * K + (K0) + ((bl1_ ^ (r1_ & 3)) << 3), &SA[c1_ * 8]); \
        gload_lds16(WT + (size_t)(col0 + r1_) * K + (K0) + ((bl1_ ^ (r1_ & 3)) << 3), &SB[c1_ * 8]); \
    }

#define G32_COMPUTE(SA, SB)                                                           \
    {                                                                                 \
        _Pragma("unroll")                                                             \
        for (int s = 0; s < 2; s++) {                                                 \
            int blk_ = s * 2 + hb;                                                    \
            short8 a0_ = *(const short8*)&SA[ra0 * 32 + ((blk_ ^ (ra0 & 3)) << 3)];   \
            short8 a1_ = *(const short8*)&SA[ra1 * 32 + ((blk_ ^ (ra1 & 3)) << 3)];   \
            short8 b0_ = *(const short8*)&SB[rb0 * 32 + ((blk_ ^ (rb0 & 3)) << 3)];   \
            short8 b1_ = *(const short8*)&SB[rb1 * 32 + ((blk_ ^ (rb1 & 3)) << 3)];   \
            acc[0][0] = __builtin_amdgcn_mfma_f32_32x32x16_bf16(a0_, b0_, acc[0][0], 0, 0, 0); \
            acc[0][1] = __builtin_amdgcn_mfma_f32_32x32x16_bf16(a0_, b1_, acc[0][1], 0, 0, 0); \
            acc[1][0] = __builtin_amdgcn_mfma_f32_32x32x16_bf16(a1_, b0_, acc[1][0], 0, 0, 0); \
            acc[1][1] = __builtin_amdgcn_mfma_f32_32x32x16_bf16(a1_, b1_, acc[1][1], 0, 0, 0); \
        }                                                                             \
    }

template<int EPI>
__launch_bounds__(256)
__global__ void gemm32(const ushort_t* __restrict__ A, const ushort_t* __restrict__ WT,
                       const float* __restrict__ bias, ushort_t* __restrict__ outB,
                       ushort_t* __restrict__ qb, ushort_t* __restrict__ kb,
                       ushort_t* __restrict__ vb, int N, int K) {
    __shared__ __align__(16) ushort_t sA0[128 * 32];
    __shared__ __align__(16) ushort_t sA1[128 * 32];
    __shared__ __align__(16) ushort_t sB0[128 * 32];
    __shared__ __align__(16) ushort_t sB1[128 * 32];
    int t = threadIdx.x;
    int row0 = blockIdx.y * 128, col0 = blockIdx.x * 128;
    int wid = t >> 6, lane = t & 63, l31 = lane & 31, hb = lane >> 5;
    int wm = wid >> 1, wn = wid & 1;
    int ra0 = wm * 64 + l31, ra1 = ra0 + 32;
    int rb0 = wn * 64 + l31, rb1 = rb0 + 32;

    floatx16 acc[2][2];
    #pragma unroll
    for (int i = 0; i < 2; i++)
        #pragma unroll
        for (int j = 0; j < 2; j++)
            #pragma unroll
            for (int e = 0; e < 16; e++) acc[i][j][e] = 0.f;

    G32_PREFETCH(0, sA0, sB0)
    for (int k0 = 0; k0 < K; k0 += 64) {
        __syncthreads();
        if (k0 + 32 < K) G32_PREFETCH(k0 + 32, sA1, sB1)
        G32_COMPUTE(sA0, sB0)
        __syncthreads();
        if (k0 + 64 < K) G32_PREFETCH(k0 + 64, sA0, sB0)
        G32_COMPUTE(sA1, sB1)
    }

    #pragma unroll
    for (int mt = 0; mt < 2; mt++) {
        #pragma unroll
        for (int nt = 0; nt < 2; nt++) {
            int gcol = col0 + wn * 64 + nt * 32 + l31;
            float bv = bias[gcol];
            if (EPI == 0) {
                int which = gcol / 768;
                int hc = gcol - which * 768;
                int hh = hc >> 6, d = hc & 63;
                #pragma unroll
                for (int rg = 0; rg < 16; rg++) {
                    int grow = row0 + wm * 64 + mt * 32 + (rg & 3) + 8 * (rg >> 2) + 4 * hb;
                    float v = acc[mt][nt][rg] + bv;
                    int b_ = grow >> 11, n = grow & 2047;
                    size_t bhh = (size_t)(b_ * 12 + hh);
                    if (which == 0)      qb[(bhh * 2048 + n) * 64 + d] = f2bf(v * 0.125f);
                    else if (which == 1) kb[(bhh * 2048 + n) * 64 + d] = f2bf(v);
                    else                 vb[(bhh * 64 + d) * 2048 + n] = f2bf(v);
                }
            } else {
                #pragma unroll
                for (int rg = 0; rg < 16; rg++) {
                    int grow = row0 + wm * 64 + mt * 32 + (rg & 3) + 8 * (rg >> 2) + 4 * hb;
                    float v = acc[mt][nt][rg] + bv;
                    v = 0.5f * v * (1.f + erff(v * 0.70710678118654752f));
                    outB[(size_t)grow * N + gcol] = f2bf(v);
                }
            }
        }
    }
}

// ---------- 16x16 GEMM (narrow proj/FC2), static double-buffered K-loop ----------
// C = A@WT^T + bias + res -> fp32

#define GB_PREFETCH(K0, SA, SB)                                                       \
    {                                                                                 \
        int r_ = t >> 2, sub_ = t & 3;                                                \
        gload_lds16(A  + (size_t)(row0 + r_) * K + (K0) + sub_ * 8, &SA[t * 8]);      \
        gload_lds16(WT + (size_t)(col0 + r_) * K + (K0) + sub_ * 8, &SB[t * 8]);      \
    }

#define GB_COMPUTE(SA, SB)                                                            \
    {                                                                                 \
        short8 a_[2], b_[2];                                                          \
        _Pragma("unroll")                                                             \
        for (int i = 0; i < 2; i++)                                                   \
            a_[i] = *(const short8*)&SA[(wm * 32 + i * 16 + cl) * 32 + quad * 8];     \
        _Pragma("unroll")                                                             \
        for (int j = 0; j < 2; j++)                                                   \
            b_[j] = *(const short8*)&SB[(wn * 32 + j * 16 + cl) * 32 + quad * 8];     \
        _Pragma("unroll")                                                             \
        for (int i = 0; i < 2; i++)                                                   \
            _Pragma("unroll")                                                         \
            for (int j = 0; j < 2; j++)                                               \
                acc[i][j] = __builtin_amdgcn_mfma_f32_16x16x32_bf16(a_[i], b_[j], acc[i][j], 0, 0, 0); \
    }

__launch_bounds__(256)
__global__ void gemm_bf16(const ushort_t* __restrict__ A, const ushort_t* __restrict__ WT,
                          const float* __restrict__ bias, const float* __restrict__ res,
                          float* __restrict__ outF, int N, int K) {
    __shared__ __align__(16) ushort_t sA0[64 * 32];
    __shared__ __align__(16) ushort_t sA1[64 * 32];
    __shared__ __align__(16) ushort_t sB0[64 * 32];
    __shared__ __align__(16) ushort_t sB1[64 * 32];
    int t = threadIdx.x;
    int row0 = blockIdx.y * 64, col0 = blockIdx.x * 64;
    int wid = t >> 6, lane = t & 63;
    int wm = wid >> 1, wn = wid & 1;
    int cl = lane & 15, quad = lane >> 4;

    floatx4 acc[2][2];
    #pragma unroll
    for (int i = 0; i < 2; i++)
        #pragma unroll
        for (int j = 0; j < 2; j++) { floatx4 z = {0.f, 0.f, 0.f, 0.f}; acc[i][j] = z; }

    GB_PREFETCH(0, sA0, sB0)
    for (int k0 = 0; k0 < K; k0 += 64) {
        __syncthreads();
        if (k0 + 32 < K) GB_PREFETCH(k0 + 32, sA1, sB1)
        GB_COMPUTE(sA0, sB0)
        __syncthreads();
        if (k0 + 64 < K) GB_PREFETCH(k0 + 64, sA0, sB0)
        GB_COMPUTE(sA1, sB1)
    }

    #pragma unroll
    for (int i = 0; i < 2; i++) {
        #pragma unroll
        for (int j = 0; j < 2; j++) {
            int gcol = col0 + wn * 32 + j * 16 + cl;
            float bv = bias[gcol];
            #pragma unroll
            for (int rg = 0; rg < 4; rg++) {
                int grow = row0 + wm * 32 + i * 16 + quad * 4 + rg;
                float v = acc[i][j][rg] + bv + res[(size_t)grow * N + gcol];
                outF[(size_t)grow * N + gcol] = v;
            }
        }
    }
}

// ---------- MFMA flash attention, 16x16x32, STATIC double-buffers (R6, unchanged) ----------
#define PREFETCH(K0N, KSN, VTN)                                                   \
    {                                                                             \
        const ushort_t* kbase_ = kb + (bh * 2048 + (K0N)) * 64;                   \
        const ushort_t* vbase_ = vb + bh * 131072 + (K0N);                        \
        int c0_ = t, r0_ = c0_ >> 3, b0_ = c0_ & 7;                               \
        gload_lds16(kbase_ + (r0_ << 6) + ((b0_ ^ (r0_ & 7)) << 3), &KSN[c0_ * 8]); \
        gload_lds16(vbase_ + (size_t)r0_ * 2048 + ((b0_ ^ (r0_ & 7)) << 3), &VTN[c0_ * 8]); \
        int c1_ = 256 + t, r1_ = c1_ >> 3, b1_ = c1_ & 7;                         \
        gload_lds16(kbase_ + (r1_ << 6) + ((b1_ ^ (r1_ & 7)) << 3), &KSN[c1_ * 8]); \
        gload_lds16(vbase_ + (size_t)r1_ * 2048 + ((b1_ ^ (r1_ & 7)) << 3), &VTN[c1_ * 8]); \
    }

#define ATTN_TILE(KT, KSC, VTC, KSN, VTN)                                         \
    {                                                                             \
        __syncthreads();                                                          \
        if ((KT) < 31) PREFETCH(((KT) + 1) * 64, KSN, VTN)                        \
        float gjv_[4];                                                            \
        gjv_[0] = G[b * 2048 + (KT) * 64 + cl];                                   \
        gjv_[1] = G[b * 2048 + (KT) * 64 + 16 + cl];                              \
        gjv_[2] = G[b * 2048 + (KT) * 64 + 32 + cl];                              \
        gjv_[3] = G[b * 2048 + (KT) * 64 + 48 + cl];                              \
        floatx4 s_[4];                                                            \
        s_[0] = c2init; s_[1] = c2init; s_[2] = c2init; s_[3] = c2init;           \
        _Pragma("unroll")                                                         \
        for (int kh = 0; kh < 2; kh++) {                                          \
            short8 aq_ = *(const short8*)&Qs[((wid * 16 + cl) << 6) + (((kh * 4 + quad) ^ (cl & 7)) << 3)]; \
            _Pragma("unroll")                                                     \
            for (int nt = 0; nt < 4; nt++) {                                      \
                short8 bk_ = *(const short8*)&KSC[((nt * 16 + cl) << 6) + (((kh * 4 + quad) ^ (cl & 7)) << 3)]; \
                s_[nt] = __builtin_amdgcn_mfma_f32_16x16x32_bf16(aq_, bk_, s_[nt], 0, 0, 0); \
            }                                                                     \
        }                                                                         \
        _Pragma("unroll")                                                         \
        for (int rg = 0; rg < 4; rg++) {                                          \
            int prow_ = wid * 16 + quad * 4 + rg;                                 \
            int r8_ = prow_ & 7, pb_ = prow_ << 6, cs_ = cl & 7, ch_ = cl >> 3;   \
            _Pragma("unroll")                                                     \
            for (int nt = 0; nt < 4; nt++) {                                      \
                float tf_ = __expf(s_[nt][rg]);                                   \
                float p_  = tf_ * __builtin_amdgcn_rcpf(gi[rg] + gjv_[nt]);       \
                sem[rg] += p_;                                                    \
                Ps[pb_ + (((nt * 2 + ch_) ^ r8_) << 3) + cs_] = (ushort_t)(__float_as_uint(p_) >> 16); \
            }                                                                     \
        }                                                                         \
        _Pragma("unroll")                                                         \
        for (int kh = 0; kh < 2; kh++) {                                          \
            short8 ap_ = *(const short8*)&Ps[((wid * 16 + cl) << 6) + (((kh * 4 + quad) ^ (cl & 7)) << 3)]; \
            _Pragma("unroll")                                                     \
            for (int dt = 0; dt < 4; dt++) {                                      \
                short8 bv_ = *(const short8*)&VTC[((dt * 16 + cl) << 6) + (((kh * 4 + quad) ^ (cl & 7)) << 3)]; \
                o[dt] = __builtin_amdgcn_mfma_f32_16x16x32_bf16(ap_, bv_, o[dt], 0, 0, 0); \
            }                                                                     \
        }                                                                         \
    }

__launch_bounds__(256)
__global__ void attn_mfma(const ushort_t* __restrict__ qb, const ushort_t* __restrict__ kb,
                          const ushort_t* __restrict__ vb, const float* __restrict__ G,
                          const float* __restrict__ C2, ushort_t* __restrict__ attn) {
    __shared__ __align__(16) ushort_t Qs[4096];
    __shared__ __align__(16) ushort_t Ks0[4096];
    __shared__ __align__(16) ushort_t Ks1[4096];
    __shared__ __align__(16) ushort_t Vt0[4096];
    __shared__ __align__(16) ushort_t Vt1[4096];
    __shared__ __align__(16) ushort_t Ps[4096];
    int qt = blockIdx.x, h = blockIdx.y, b = blockIdx.z;
    int t = threadIdx.x, wid = t >> 6, lane = t & 63;
    int cl = lane & 15, quad = lane >> 4;
    int q0 = qt * 64;
    size_t bh = (size_t)(b * 12 + h);

    const ushort_t* qbase = qb + (bh * 2048 + q0) * 64;
    #pragma unroll
    for (int i = 0; i < 2; i++) {
        int c = i * 256 + t, row = c >> 3, blk = c & 7;
        gload_lds16(qbase + (row << 6) + ((blk ^ (row & 7)) << 3), &Qs[c * 8]);
    }
    int qrow4 = b * 2048 + q0 + wid * 16 + quad * 4;
    float4 g4  = *(const float4*)(G  + qrow4);
    float4 c24 = *(const float4*)(C2 + qrow4);
    float gi[4]  = {g4.x, g4.y, g4.z, g4.w};
    floatx4 c2init = {c24.x, c24.y, c24.z, c24.w};

    PREFETCH(0, Ks0, Vt0)

    floatx4 o[4];
    #pragma unroll
    for (int j = 0; j < 4; j++) { floatx4 z = {0.f, 0.f, 0.f, 0.f}; o[j] = z; }
    float sem[4] = {0.f, 0.f, 0.f, 0.f};

    for (int kt = 0; kt < 32; kt += 2) {
        ATTN_TILE(kt,     Ks0, Vt0, Ks1, Vt1)
        ATTN_TILE(kt + 1, Ks1, Vt1, Ks0, Vt0)
    }

    #pragma unroll
    for (int rg = 0; rg < 4; rg++) {
        float m = sem[rg];
        #pragma unroll
        for (int off = 1; off < 16; off <<= 1) m += __shfl_xor(m, off);
        float inv = __builtin_amdgcn_rcpf(m);
        int grow = b * 2048 + q0 + wid * 16 + quad * 4 + rg;
        #pragma unroll
        for (int dt = 0; dt < 4; dt++)
            attn[(size_t)grow * 768 + h * 64 + dt * 16 + cl] = f2bf(o[dt][rg] * inv);
    }
}

extern "C" void kernel_launch(void* const* d_in, const int* in_sizes, int n_in,
                              void* d_out, int out_size, void* d_ws, size_t ws_size,
                              hipStream_t stream) {
    const float* x      = (const float*)d_in[0];
    const float* elev   = (const float*)d_in[1];
    const float* qkv_w  = (const float*)d_in[2];
    const float* qkv_b  = (const float*)d_in[3];
    const float* proj_w = (const float*)d_in[4];
    const float* proj_b = (const float*)d_in[5];
    const float* ln1_g  = (const float*)d_in[6];
    const float* ln1_b  = (const float*)d_in[7];
    const float* ln2_g  = (const float*)d_in[8];
    const float* ln2_b  = (const float*)d_in[9];
    const float* fc1_w  = (const float*)d_in[10];
    const float* fc1_b  = (const float*)d_in[11];
    const float* fc2_w  = (const float*)d_in[12];
    const float* fc2_b  = (const float*)d_in[13];
    const float* barrier= (const float*)d_in[14];
    float* out = (float*)d_out;
    char* ws = (char*)d_ws;

    ushort_t* h    = (ushort_t*)(ws + 0);         // 6291456 B
    ushort_t* qb   = (ushort_t*)(ws + 6291456);   // 6291456
    ushort_t* kb   = (ushort_t*)(ws + 12582912);  // 6291456
    ushort_t* vb   = (ushort_t*)(ws + 18874368);  // 6291456
    ushort_t* f1   = (ushort_t*)(ws + 0);         // 25165824 (overlays h,qb,kb,vb)
    ushort_t* attn = (ushort_t*)(ws + 25165824);  // 6291456
    ushort_t* h2   = (ushort_t*)(ws + 31457280);  // 6291456
    float*    Gf   = (float*)(ws + 31457280);     // overlays h2 region, dead before ln2
    float*    C2f  = (float*)(ws + 31473664);
    ushort_t* qkvT = (ushort_t*)(ws + 37748736);  // 3538944
    ushort_t* projT= (ushort_t*)(ws + 41287680);  // 1179648
    ushort_t* fc1T = (ushort_t*)(ws + 42467328);  // 4718592
    ushort_t* fc2T = (ushort_t*)(ws + 47185920);  // 4718592

    wconv_all<<<1728, 256, 0, stream>>>(qkv_w, proj_w, fc1_w, fc2_w, qkvT, projT, fc1T, fc2T);
    gelev_kernel<<<16, 256, 0, stream>>>(elev, barrier, Gf, C2f);

    ln_kernel<<<ROWS, 256, 0, stream>>>(x, ln1_g, ln1_b, h);
    gemm32<0><<<dim3(2304 / 128, 32), 256, 0, stream>>>(
        h, qkvT, qkv_b, nullptr, qb, kb, vb, 2304, 768);
    attn_mfma<<<dim3(32, HEADS, 2), 256, 0, stream>>>(qb, kb, vb, Gf, C2f, attn);
    gemm_bf16<<<dim3(768 / 64, 64), 256, 0, stream>>>(
        attn, projT, proj_b, x, out, 768, 768);
    ln_kernel<<<ROWS, 256, 0, stream>>>(out, ln2_g, ln2_b, h2);
    gemm32<1><<<dim3(3072 / 128, 32), 256, 0, stream>>>(
        h2, fc1T, fc1_b, f1, nullptr, nullptr, nullptr, 3072, 768);
    gemm_bf16<<<dim3(768 / 64, 64), 256, 0, stream>>>(
        f1, fc2T, fc2_b, out, out, 768, 3072);
}

// Round 8
// 312.793 us; speedup vs baseline: 6.2696x; 1.0226x over previous
//
#include <hip/hip_runtime.h>
#include <math.h>

#define DIM 768
#define HEADS 12
#define SEQ 2048
#define ROWS 4096
#define LN_EPS 1e-5f

typedef __attribute__((ext_vector_type(8))) short short8;
typedef __attribute__((ext_vector_type(4))) float floatx4;
typedef __attribute__((ext_vector_type(16))) float floatx16;
typedef unsigned short ushort_t;

__device__ __forceinline__ ushort_t f2bf(float x) {
    unsigned u = __float_as_uint(x);
    u += 0x7fff + ((u >> 16) & 1);
    return (ushort_t)(u >> 16);
}

__device__ __forceinline__ void gload_lds16(const void* g, void* l) {
    __builtin_amdgcn_global_load_lds((const __attribute__((address_space(1))) void*)g,
                                     (__attribute__((address_space(3))) void*)l, 16, 0, 0);
}

// ---------- fused prep: weight convert (blocks 0..1727) + gelev (1728..1743)
// ---------- + ln1 (1744..5839). All independent.
__launch_bounds__(256)
__global__ void prep_all(const float* __restrict__ w0, const float* __restrict__ w1,
                         const float* __restrict__ w2, const float* __restrict__ w3,
                         ushort_t* __restrict__ t0, ushort_t* __restrict__ t1,
                         ushort_t* __restrict__ t2, ushort_t* __restrict__ t3,
                         const float* __restrict__ elev, const float* __restrict__ barrier_p,
                         float* __restrict__ G, float* __restrict__ C2,
                         const float* __restrict__ x, const float* __restrict__ ln1_g,
                         const float* __restrict__ ln1_b, ushort_t* __restrict__ h) {
    __shared__ __align__(16) ushort_t s[64][72];
    int bid = blockIdx.x;
    int t = threadIdx.x;
    if (bid < 1728) {
        const float* W; ushort_t* WT; int K, N, nx, id;
        if (bid < 432)       { W = w0; WT = t0; K = 768;  N = 2304; nx = 36; id = bid; }
        else if (bid < 576)  { W = w1; WT = t1; K = 768;  N = 768;  nx = 12; id = bid - 432; }
        else if (bid < 1152) { W = w2; WT = t2; K = 768;  N = 3072; nx = 48; id = bid - 576; }
        else                 { W = w3; WT = t3; K = 3072; N = 768;  nx = 12; id = bid - 1152; }
        int tx = id % nx, ty = id / nx;
        int k0 = ty * 64, n0 = tx * 64;
        int rr0 = t >> 4, c4 = (t & 15) * 4;
        for (int rr = rr0; rr < 64; rr += 16) {
            float4 w = *(const float4*)(W + (size_t)(k0 + rr) * N + n0 + c4);
            s[c4 + 0][rr] = f2bf(w.x); s[c4 + 1][rr] = f2bf(w.y);
            s[c4 + 2][rr] = f2bf(w.z); s[c4 + 3][rr] = f2bf(w.w);
        }
        __syncthreads();
        int nl = t >> 2, kq = (t & 3) * 16;
        uint4 a = *(const uint4*)&s[nl][kq];
        uint4 b = *(const uint4*)&s[nl][kq + 8];
        *(uint4*)(WT + (size_t)(n0 + nl) * K + k0 + kq) = a;
        *(uint4*)(WT + (size_t)(n0 + nl) * K + k0 + kq + 8) = b;
    } else if (bid < 1744) {
        int i = (bid - 1728) * 256 + t;
        float be = barrier_p[0] * elev[i];
        G[i]  = __expf(be);
        C2[i] = be;
    } else {
        int row = bid - 1744;
        const float* xr = x + (size_t)row * DIM;
        float v0 = xr[t], v1 = xr[t + 256], v2 = xr[t + 512];
        float sm  = v0 + v1 + v2;
        float ss = v0 * v0 + v1 * v1 + v2 * v2;
        #pragma unroll
        for (int o = 32; o >= 1; o >>= 1) { sm += __shfl_xor(sm, o); ss += __shfl_xor(ss, o); }
        __shared__ float rs[4], rss[4];
        int wid = t >> 6, lane = t & 63;
        if (lane == 0) { rs[wid] = sm; rss[wid] = ss; }
        __syncthreads();
        if (t == 0) {
            float S = 0.f, SS = 0.f;
            for (int i2 = 0; i2 < 4; i2++) { S += rs[i2]; SS += rss[i2]; }
            rs[0] = S; rss[0] = SS;
        }
        __syncthreads();
        float mean = rs[0] * (1.0f / DIM);
        float var  = rss[0] * (1.0f / DIM) - mean * mean;
        float rstd = rsqrtf(var + LN_EPS);
        ushort_t* orow = h + (size_t)row * DIM;
        orow[t]       = f2bf((v0 - mean) * rstd * ln1_g[t]       + ln1_b[t]);
        orow[t + 256] = f2bf((v1 - mean) * rstd * ln1_g[t + 256] + ln1_b[t + 256]);
        orow[t + 512] = f2bf((v2 - mean) * rstd * ln1_g[t + 512] + ln1_b[t + 512]);
    }
}

// ---------- LayerNorm fp32 in -> bf16 out (ln2) ----------
__launch_bounds__(256)
__global__ void ln_kernel(const float* __restrict__ x, const float* __restrict__ g,
                          const float* __restrict__ b, ushort_t* __restrict__ out) {
    int row = blockIdx.x;
    const float* xr = x + (size_t)row * DIM;
    int t = threadIdx.x;
    float v0 = xr[t], v1 = xr[t + 256], v2 = xr[t + 512];
    float s  = v0 + v1 + v2;
    float ss = v0 * v0 + v1 * v1 + v2 * v2;
    #pragma unroll
    for (int o = 32; o >= 1; o >>= 1) { s += __shfl_xor(s, o); ss += __shfl_xor(ss, o); }
    __shared__ float rs[4], rss[4];
    int wid = t >> 6, lane = t & 63;
    if (lane == 0) { rs[wid] = s; rss[wid] = ss; }
    __syncthreads();
    if (t == 0) {
        float S = 0.f, SS = 0.f;
        for (int i = 0; i < 4; i++) { S += rs[i]; SS += rss[i]; }
        rs[0] = S; rss[0] = SS;
    }
    __syncthreads();
    float mean = rs[0] * (1.0f / DIM);
    float var  = rss[0] * (1.0f / DIM) - mean * mean;
    float rstd = rsqrtf(var + LN_EPS);
    ushort_t* orow = out + (size_t)row * DIM;
    orow[t]       = f2bf((v0 - mean) * rstd * g[t]       + b[t]);
    orow[t + 256] = f2bf((v1 - mean) * rstd * g[t + 256] + b[t + 256]);
    orow[t + 512] = f2bf((v2 - mean) * rstd * g[t + 512] + b[t + 512]);
}

// ---------- 128x128 bf16 GEMM, 16x16x32 MFMA, 4x4 acc, static dbuf ----------
// Swizzle: LDS[r*32+bl*8] = G[r][(bl^((r^(r>>2))&3))*8]; frag read inverts it.
// EPI 0: qkv scatter   EPI 1: gelu -> bf16

#define G16_PREFETCH(K0, SA, SB)                                                      \
    {                                                                                 \
        int c0_ = t, r0_ = c0_ >> 2, bl0_ = c0_ & 3;                                  \
        int sw0_ = bl0_ ^ ((r0_ ^ (r0_ >> 2)) & 3);                                   \
        gload_lds16(A  + (size_t)(row0 + r0_) * K + (K0) + (sw0_ << 3), &SA[c0_ * 8]); \
        gload_lds16(WT + (size_t)(col0 + r0_) * K + (K0) + (sw0_ << 3), &SB[c0_ * 8]); \
        int c1_ = 256 + t, r1_ = c1_ >> 2, bl1_ = c1_ & 3;                            \
        int sw1_ = bl1_ ^ ((r1_ ^ (r1_ >> 2)) & 3);                                   \
        gload_lds16(A  + (size_t)(row0 + r1_) * K + (K0) + (sw1_ << 3), &SA[c1_ * 8]); \
        gload_lds16(WT + (size_t)(col0 + r1_) * K + (K0) + (sw1_ << 3), &SB[c1_ * 8]); \
    }

#define G16_COMPUTE(SA, SB)                                                           \
    {                                                                                 \
        short8 a_[4], b_[4];                                                          \
        _Pragma("unroll")                                                             \
        for (int i = 0; i < 4; i++) {                                                 \
            int ra_ = wm * 64 + i * 16 + cl;                                          \
            a_[i] = *(const short8*)&SA[ra_ * 32 + ((quad ^ ((ra_ ^ (ra_ >> 2)) & 3)) << 3)]; \
        }                                                                             \
        _Pragma("unroll")                                                             \
        for (int j = 0; j < 4; j++) {                                                 \
            int rb_ = wn * 64 + j * 16 + cl;                                          \
            b_[j] = *(const short8*)&SB[rb_ * 32 + ((quad ^ ((rb_ ^ (rb_ >> 2)) & 3)) << 3)]; \
        }                                                                             \
        _Pragma("unroll")                                                             \
        for (int i = 0; i < 4; i++)                                                   \
            _Pragma("unroll")                                                         \
            for (int j = 0; j < 4; j++)                                               \
                acc[i][j] = __builtin_amdgcn_mfma_f32_16x16x32_bf16(a_[i], b_[j], acc[i][j], 0, 0, 0); \
    }

template<int EPI>
__launch_bounds__(256)
__global__ void gemm16(const ushort_t* __restrict__ A, const ushort_t* __restrict__ WT,
                       const float* __restrict__ bias, ushort_t* __restrict__ outB,
                       ushort_t* __restrict__ qb, ushort_t* __restrict__ kb,
                       ushort_t* __restrict__ vb, int N, int K) {
    __shared__ __align__(16) ushort_t sA0[128 * 32];
    __shared__ __align__(16) ushort_t sA1[128 * 32];
    __shared__ __align__(16) ushort_t sB0[128 * 32];
    __shared__ __align__(16) ushort_t sB1[128 * 32];
    int t = threadIdx.x;
    int row0 = blockIdx.y * 128, col0 = blockIdx.x * 128;
    int wid = t >> 6, lane = t & 63;
    int wm = wid >> 1, wn = wid & 1;
    int cl = lane & 15, quad = lane >> 4;

    floatx4 acc[4][4];
    #pragma unroll
    for (int i = 0; i < 4; i++)
        #pragma unroll
        for (int j = 0; j < 4; j++) { floatx4 z = {0.f, 0.f, 0.f, 0.f}; acc[i][j] = z; }

    G16_PREFETCH(0, sA0, sB0)
    for (int k0 = 0; k0 < K; k0 += 64) {
        __syncthreads();
        if (k0 + 32 < K) G16_PREFETCH(k0 + 32, sA1, sB1)
        G16_COMPUTE(sA0, sB0)
        __syncthreads();
        if (k0 + 64 < K) G16_PREFETCH(k0 + 64, sA0, sB0)
        G16_COMPUTE(sA1, sB1)
    }

    #pragma unroll
    for (int i = 0; i < 4; i++) {
        #pragma unroll
        for (int j = 0; j < 4; j++) {
            int gcol = col0 + wn * 64 + j * 16 + cl;
            float bv = bias[gcol];
            #pragma unroll
            for (int rg = 0; rg < 4; rg++) {
                int grow = row0 + wm * 64 + i * 16 + quad * 4 + rg;
                float v = acc[i][j][rg] + bv;
                if (EPI == 0) {
                    int which = gcol / 768;
                    int hc = gcol - which * 768;
                    int hh = hc >> 6, d = hc & 63;
                    int b_ = grow >> 11, n = grow & 2047;
                    size_t bhh = (size_t)(b_ * 12 + hh);
                    if (which == 0)      qb[(bhh * 2048 + n) * 64 + d] = f2bf(v * 0.125f);
                    else if (which == 1) kb[(bhh * 2048 + n) * 64 + d] = f2bf(v);
                    else                 vb[(bhh * 64 + d) * 2048 + n] = f2bf(v);
                } else {
                    v = 0.5f * v * (1.f + erff(v * 0.70710678118654752f));
                    outB[(size_t)grow * N + gcol] = f2bf(v);
                }
            }
        }
    }
}

// ---------- 16x16 GEMM (narrow proj/FC2), static double-buffered K-loop ----------
#define GB_PREFETCH(K0, SA, SB)                                                       \
    {                                                                                 \
        int r_ = t >> 2, sub_ = t & 3;                                                \
        gload_lds16(A  + (size_t)(row0 + r_) * K + (K0) + sub_ * 8, &SA[t * 8]);      \
        gload_lds16(WT + (size_t)(col0 + r_) * K + (K0) + sub_ * 8, &SB[t * 8]);      \
    }

#define GB_COMPUTE(SA, SB)                                                            \
    {                                                                                 \
        short8 a_[2], b_[2];                                                          \
        _Pragma("unroll")                                                             \
        for (int i = 0; i < 2; i++)                                                   \
            a_[i] = *(const short8*)&SA[(wm * 32 + i * 16 + cl) * 32 + quad * 8];     \
        _Pragma("unroll")                                                             \
        for (int j = 0; j < 2; j++)                                                   \
            b_[j] = *(const short8*)&SB[(wn * 32 + j * 16 + cl) * 32 + quad * 8];     \
        _Pragma("unroll")                                                             \
        for (int i = 0; i < 2; i++)                                                   \
            _Pragma("unroll")                                                         \
            for (int j = 0; j < 2; j++)                                               \
                acc[i][j] = __builtin_amdgcn_mfma_f32_16x16x32_bf16(a_[i], b_[j], acc[i][j], 0, 0, 0); \
    }

__launch_bounds__(256)
__global__ void gemm_bf16(const ushort_t* __restrict__ A, const ushort_t* __restrict__ WT,
                          const float* __restrict__ bias, const float* __restrict__ res,
                          float* __restrict__ outF, int N, int K) {
    __shared__ __align__(16) ushort_t sA0[64 * 32];
    __shared__ __align__(16) ushort_t sA1[64 * 32];
    __shared__ __align__(16) ushort_t sB0[64 * 32];
    __shared__ __align__(16) ushort_t sB1[64 * 32];
    int t = threadIdx.x;
    int row0 = blockIdx.y * 64, col0 = blockIdx.x * 64;
    int wid = t >> 6, lane = t & 63;
    int wm = wid >> 1, wn = wid & 1;
    int cl = lane & 15, quad = lane >> 4;

    floatx4 acc[2][2];
    #pragma unroll
    for (int i = 0; i < 2; i++)
        #pragma unroll
        for (int j = 0; j < 2; j++) { floatx4 z = {0.f, 0.f, 0.f, 0.f}; acc[i][j] = z; }

    GB_PREFETCH(0, sA0, sB0)
    for (int k0 = 0; k0 < K; k0 += 64) {
        __syncthreads();
        if (k0 + 32 < K) GB_PREFETCH(k0 + 32, sA1, sB1)
        GB_COMPUTE(sA0, sB0)
        __syncthreads();
        if (k0 + 64 < K) GB_PREFETCH(k0 + 64, sA0, sB0)
        GB_COMPUTE(sA1, sB1)
    }

    #pragma unroll
    for (int i = 0; i < 2; i++) {
        #pragma unroll
        for (int j = 0; j < 2; j++) {
            int gcol = col0 + wn * 32 + j * 16 + cl;
            float bv = bias[gcol];
            #pragma unroll
            for (int rg = 0; rg < 4; rg++) {
                int grow = row0 + wm * 32 + i * 16 + quad * 4 + rg;
                float v = acc[i][j][rg] + bv + res[(size_t)grow * N + gcol];
                outF[(size_t)grow * N + gcol] = v;
            }
        }
    }
}

// ---------- MFMA flash attention, 16x16x32, STATIC double-buffers (R6) ----------
#define PREFETCH(K0N, KSN, VTN)                                                   \
    {                                                                             \
        const ushort_t* kbase_ = kb + (bh * 2048 + (K0N)) * 64;                   \
        const ushort_t* vbase_ = vb + bh * 131072 + (K0N);                        \
        int c0_ = t, r0_ = c0_ >> 3, b0_ = c0_ & 7;                               \
        gload_lds16(kbase_ + (r0_ << 6) + ((b0_ ^ (r0_ & 7)) << 3), &KSN[c0_ * 8]); \
        gload_lds16(vbase_ + (size_t)r0_ * 2048 + ((b0_ ^ (r0_ & 7)) << 3), &VTN[c0_ * 8]); \
        int c1_ = 256 + t, r1_ = c1_ >> 3, b1_ = c1_ & 7;                         \
        gload_lds16(kbase_ + (r1_ << 6) + ((b1_ ^ (r1_ & 7)) << 3), &KSN[c1_ * 8]); \
        gload_lds16(vbase_ + (size_t)r1_ * 2048 + ((b1_ ^ (r1_ & 7)) << 3), &VTN[c1_ * 8]); \
    }

#define ATTN_TILE(KT, KSC, VTC, KSN, VTN)                                         \
    {                                                                             \
        __syncthreads();                                                          \
        if ((KT) < 31) PREFETCH(((KT) + 1) * 64, KSN, VTN)                        \
        float gjv_[4];                                                            \
        gjv_[0] = G[b * 2048 + (KT) * 64 + cl];                                   \
        gjv_[1] = G[b * 2048 + (KT) * 64 + 16 + cl];                              \
        gjv_[2] = G[b * 2048 + (KT) * 64 + 32 + cl];                              \
        gjv_[3] = G[b * 2048 + (KT) * 64 + 48 + cl];                              \
        floatx4 s_[4];                                                            \
        s_[0] = c2init; s_[1] = c2init; s_[2] = c2init; s_[3] = c2init;           \
        _Pragma("unroll")                                                         \
        for (int kh = 0; kh < 2; kh++) {                                          \
            short8 aq_ = *(const short8*)&Qs[((wid * 16 + cl) << 6) + (((kh * 4 + quad) ^ (cl & 7)) << 3)]; \
            _Pragma("unroll")                                                     \
            for (int nt = 0; nt < 4; nt++) {                                      \
                short8 bk_ = *(const short8*)&KSC[((nt * 16 + cl) << 6) + (((kh * 4 + quad) ^ (cl & 7)) << 3)]; \
                s_[nt] = __builtin_amdgcn_mfma_f32_16x16x32_bf16(aq_, bk_, s_[nt], 0, 0, 0); \
            }                                                                     \
        }                                                                         \
        _Pragma("unroll")                                                         \
        for (int rg = 0; rg < 4; rg++) {                                          \
            int prow_ = wid * 16 + quad * 4 + rg;                                 \
            int r8_ = prow_ & 7, pb_ = prow_ << 6, cs_ = cl & 7, ch_ = cl >> 3;   \
            _Pragma("unroll")                                                     \
            for (int nt = 0; nt < 4; nt++) {                                      \
                float tf_ = __expf(s_[nt][rg]);                                   \
                float p_  = tf_ * __builtin_amdgcn_rcpf(gi[rg] + gjv_[nt]);       \
                sem[rg] += p_;                                                    \
                Ps[pb_ + (((nt * 2 + ch_) ^ r8_) << 3) + cs_] = (ushort_t)(__float_as_uint(p_) >> 16); \
            }                                                                     \
        }                                                                         \
        _Pragma("unroll")                                                         \
        for (int kh = 0; kh < 2; kh++) {                                          \
            short8 ap_ = *(const short8*)&Ps[((wid * 16 + cl) << 6) + (((kh * 4 + quad) ^ (cl & 7)) << 3)]; \
            _Pragma("unroll")                                                     \
            for (int dt = 0; dt < 4; dt++) {                                      \
                short8 bv_ = *(const short8*)&VTC[((dt * 16 + cl) << 6) + (((kh * 4 + quad) ^ (cl & 7)) << 3)]; \
                o[dt] = __builtin_amdgcn_mfma_f32_16x16x32_bf16(ap_, bv_, o[dt], 0, 0, 0); \
            }                                                                     \
        }                                                                         \
    }

__launch_bounds__(256)
__global__ void attn_mfma(const ushort_t* __restrict__ qb, const ushort_t* __restrict__ kb,
                          const ushort_t* __restrict__ vb, const float* __restrict__ G,
                          const float* __restrict__ C2, ushort_t* __restrict__ attn) {
    __shared__ __align__(16) ushort_t Qs[4096];
    __shared__ __align__(16) ushort_t Ks0[4096];
    __shared__ __align__(16) ushort_t Ks1[4096];
    __shared__ __align__(16) ushort_t Vt0[4096];
    __shared__ __align__(16) ushort_t Vt1[4096];
    __shared__ __align__(16) ushort_t Ps[4096];
    int qt = blockIdx.x, h = blockIdx.y, b = blockIdx.z;
    int t = threadIdx.x, wid = t >> 6, lane = t & 63;
    int cl = lane & 15, quad = lane >> 4;
    int q0 = qt * 64;
    size_t bh = (size_t)(b * 12 + h);

    const ushort_t* qbase = qb + (bh * 2048 + q0) * 64;
    #pragma unroll
    for (int i = 0; i < 2; i++) {
        int c = i * 256 + t, row = c >> 3, blk = c & 7;
        gload_lds16(qbase + (row << 6) + ((blk ^ (row & 7)) << 3), &Qs[c * 8]);
    }
    int qrow4 = b * 2048 + q0 + wid * 16 + quad * 4;
    float4 g4  = *(const float4*)(G  + qrow4);
    float4 c24 = *(const float4*)(C2 + qrow4);
    float gi[4]  = {g4.x, g4.y, g4.z, g4.w};
    floatx4 c2init = {c24.x, c24.y, c24.z, c24.w};

    PREFETCH(0, Ks0, Vt0)

    floatx4 o[4];
    #pragma unroll
    for (int j = 0; j < 4; j++) { floatx4 z = {0.f, 0.f, 0.f, 0.f}; o[j] = z; }
    float sem[4] = {0.f, 0.f, 0.f, 0.f};

    for (int kt = 0; kt < 32; kt += 2) {
        ATTN_TILE(kt,     Ks0, Vt0, Ks1, Vt1)
        ATTN_TILE(kt + 1, Ks1, Vt1, Ks0, Vt0)
    }

    #pragma unroll
    for (int rg = 0; rg < 4; rg++) {
        float m = sem[rg];
        #pragma unroll
        for (int off = 1; off < 16; off <<= 1) m += __shfl_xor(m, off);
        float inv = __builtin_amdgcn_rcpf(m);
        int grow = b * 2048 + q0 + wid * 16 + quad * 4 + rg;
        #pragma unroll
        for (int dt = 0; dt < 4; dt++)
            attn[(size_t)grow * 768 + h * 64 + dt * 16 + cl] = f2bf(o[dt][rg] * inv);
    }
}

extern "C" void kernel_launch(void* const* d_in, const int* in_sizes, int n_in,
                              void* d_out, int out_size, void* d_ws, size_t ws_size,
                              hipStream_t stream) {
    const float* x      = (const float*)d_in[0];
    const float* elev   = (const float*)d_in[1];
    const float* qkv_w  = (const float*)d_in[2];
    const float* qkv_b  = (const float*)d_in[3];
    const float* proj_w = (const float*)d_in[4];
    const float* proj_b = (const float*)d_in[5];
    const float* ln1_g  = (const float*)d_in[6];
    const float* ln1_b  = (const float*)d_in[7];
    const float* ln2_g  = (const float*)d_in[8];
    const float* ln2_b  = (const float*)d_in[9];
    const float* fc1_w  = (const float*)d_in[10];
    const float* fc1_b  = (const float*)d_in[11];
    const float* fc2_w  = (const float*)d_in[12];
    const float* fc2_b  = (const float*)d_in[13];
    const float* barrier= (const float*)d_in[14];
    float* out = (float*)d_out;
    char* ws = (char*)d_ws;

    ushort_t* h    = (ushort_t*)(ws + 0);         // 6291456 B
    ushort_t* qb   = (ushort_t*)(ws + 6291456);   // 6291456
    ushort_t* kb   = (ushort_t*)(ws + 12582912);  // 6291456
    ushort_t* vb   = (ushort_t*)(ws + 18874368);  // 6291456
    ushort_t* f1   = (ushort_t*)(ws + 0);         // 25165824 (overlays h,qb,kb,vb)
    ushort_t* attn = (ushort_t*)(ws + 25165824);  // 6291456
    ushort_t* h2   = (ushort_t*)(ws + 31457280);  // 6291456
    float*    Gf   = (float*)(ws + 31457280);     // overlays h2 region, dead before ln2
    float*    C2f  = (float*)(ws + 31473664);
    ushort_t* qkvT = (ushort_t*)(ws + 37748736);  // 3538944
    ushort_t* projT= (ushort_t*)(ws + 41287680);  // 1179648
    ushort_t* fc1T = (ushort_t*)(ws + 42467328);  // 4718592
    ushort_t* fc2T = (ushort_t*)(ws + 47185920);  // 4718592

    prep_all<<<5840, 256, 0, stream>>>(qkv_w, proj_w, fc1_w, fc2_w, qkvT, projT, fc1T, fc2T,
                                       elev, barrier, Gf, C2f, x, ln1_g, ln1_b, h);
    gemm16<0><<<dim3(2304 / 128, 32), 256, 0, stream>>>(
        h, qkvT, qkv_b, nullptr, qb, kb, vb, 2304, 768);
    attn_mfma<<<dim3(32, HEADS, 2), 256, 0, stream>>>(qb, kb, vb, Gf, C2f, attn);
    gemm_bf16<<<dim3(768 / 64, 64), 256, 0, stream>>>(
        attn, projT, proj_b, x, out, 768, 768);
    ln_kernel<<<ROWS, 256, 0, stream>>>(out, ln2_g, ln2_b, h2);
    gemm16<1><<<dim3(3072 / 128, 32), 256, 0, stream>>>(
        h2, fc1T, fc1_b, f1, nullptr, nullptr, nullptr, 3072, 768);
    gemm_bf16<<<dim3(768 / 64, 64), 256, 0, stream>>>(
        f1, fc2T, fc2_b, out, out, 768, 3072);
}